// Round 1
// baseline (1636.104 us; speedup 1.0000x reference)
//
#include <hip/hip_runtime.h>
#include <math.h>

#define BB 8
#define NN 2048
#define DD 256
#define MTOK 16384

// ---- workspace layout (float offsets) ----
#define OFF_NORMED 0ull
#define OFF_H      4194304ull
#define OFF_Q      8388608ull
#define OFF_K      12582912ull
#define OFF_FS     16777216ull
#define OFF_P      20971520ull
#define OFF_MSG    OFF_NORMED   // msg overwrites normed (dead after P projection)
#define OFF_GM     OFF_H        // gate*msg overwrites h (dead after projections)
#define OFF_ENT    25165824ull
#define OFF_MONR   (OFF_ENT + 16384ull)
#define OFF_HUBR   (OFF_MONR + 16384ull)
#define OFF_MONF   (OFF_HUBR + 16384ull)
#define OFF_HUBF   (OFF_MONF + 2048ull)
#define OFF_MASK   (OFF_HUBF + 2048ull)   // 16384 bytes (= 4096 floats)
#define OFF_KIND   (OFF_MASK + 4096ull)

// ---------------- mask dtype detection ----------------
// node_mask is bool in the reference; the ABI may hand us bool-bytes, int32,
// or float32. Distinguish by byte pattern of the first 16384 bytes:
//   int32 0/1 : bytes at i%4!=0 all zero           -> kind 0
//   bool byte : nonzeros at both i%4==0 and i%4!=0 -> kind 1
//   float 0/1 : bytes at i%4==0 all zero (LSB of 1.0f is 0) -> kind 2
__global__ __launch_bounds__(256) void detect_mask_kernel(
    const unsigned char* __restrict__ mraw, int* __restrict__ kind) {
  __shared__ int c0s, c1s;
  if (threadIdx.x == 0) { c0s = 0; c1s = 0; }
  __syncthreads();
  int c0 = 0, c1 = 0;
  for (int i = threadIdx.x; i < MTOK; i += 256) {
    int nz = (mraw[i] != 0) ? 1 : 0;
    if ((i & 3) == 0) c0 += nz; else c1 += nz;
  }
  atomicAdd(&c0s, c0);
  atomicAdd(&c1s, c1);
  __syncthreads();
  if (threadIdx.x == 0) {
    int k;
    if (c0s == 0) k = 2;       // float32 layout
    else if (c1s == 0) k = 0;  // int32 layout
    else k = 1;                // byte layout
    *kind = k;
  }
}

__global__ __launch_bounds__(256) void build_mask_kernel(
    const void* __restrict__ mraw, const int* __restrict__ roles,
    const int* __restrict__ kind, unsigned char* __restrict__ mask8,
    float* __restrict__ monf, float* __restrict__ hubf) {
  int t = blockIdx.x * 256 + threadIdx.x;
  if (t < MTOK) {
    int k = *kind;
    int v;
    if (k == 1)      v = (((const unsigned char*)mraw)[t] != 0);
    else if (k == 0) v = (((const int*)mraw)[t] != 0);
    else             v = (((const float*)mraw)[t] != 0.0f);
    mask8[t] = (unsigned char)v;
  }
  if (t < NN) {
    int mon = 0, hub = 0;
#pragma unroll
    for (int b = 0; b < BB; ++b) {
      int r = roles[b * NN + t];
      mon |= (r == 2) ? 1 : 0;   // ROLE_MONITOR
      hub |= (r == 1) ? 1 : 0;   // ROLE_HUB
    }
    monf[t] = (float)mon;
    hubf[t] = (float)hub;
  }
}

// ---------------- layernorm + role bias (one wave per token) ----------------
__global__ __launch_bounds__(256) void prep_kernel(
    const float* __restrict__ x, const int* __restrict__ roles,
    const float* __restrict__ gamma, const float* __restrict__ beta,
    const float* __restrict__ role_emb,
    float* __restrict__ normed, float* __restrict__ h) {
  int t = blockIdx.x * 4 + (threadIdx.x >> 6);
  int lane = threadIdx.x & 63;
  size_t off = (size_t)t * DD + lane * 4;
  float4 xv = *(const float4*)(x + off);
  float s = xv.x + xv.y + xv.z + xv.w;
  float ss = xv.x * xv.x + xv.y * xv.y + xv.z * xv.z + xv.w * xv.w;
#pragma unroll
  for (int m = 1; m < 64; m <<= 1) {
    s += __shfl_xor(s, m, 64);
    ss += __shfl_xor(ss, m, 64);
  }
  float mu = s * (1.0f / 256.0f);
  float var = ss * (1.0f / 256.0f) - mu * mu;
  float inv = rsqrtf(var + 1e-5f);
  float4 g = *(const float4*)(gamma + lane * 4);
  float4 be = *(const float4*)(beta + lane * 4);
  float4 nv;
  nv.x = (xv.x - mu) * inv * g.x + be.x;
  nv.y = (xv.y - mu) * inv * g.y + be.y;
  nv.z = (xv.z - mu) * inv * g.z + be.z;
  nv.w = (xv.w - mu) * inv * g.w + be.w;
  *(float4*)(normed + off) = nv;
  int role = roles[t];
  float4 rb = *(const float4*)(role_emb + (size_t)role * DD + lane * 4);
  float4 hv;
  hv.x = nv.x + rb.x; hv.y = nv.y + rb.y; hv.z = nv.z + rb.z; hv.w = nv.w + rb.w;
  *(float4*)(h + off) = hv;
}

// ---------------- f32 tiled GEMM: C[M=16384,256] = A[.,256] @ W[256,256] + b ----
// EPI 0: +bias. EPI 1: +bias +role_emb[roles[row]] (the fs = role_bias + sender path)
template <int EPI>
__global__ __launch_bounds__(256) void gemm256_kernel(
    const float* __restrict__ A, const float* __restrict__ W,
    const float* __restrict__ bias, float* __restrict__ C,
    const int* __restrict__ roles, const float* __restrict__ role_emb) {
  __shared__ float As[16][68];
  __shared__ float Bs[16][68];
  int tid = threadIdx.x;
  int ty = tid >> 4, tx = tid & 15;
  int row0 = blockIdx.y * 64, col0 = blockIdx.x * 64;
  int ar = tid >> 2, ac4 = tid & 3;
  int bk = tid >> 4, bn4 = tid & 15;
  float acc[4][4] = {};
  for (int k0 = 0; k0 < DD; k0 += 16) {
    __syncthreads();
    float4 a = *(const float4*)(A + (size_t)(row0 + ar) * DD + k0 + ac4 * 4);
    As[ac4 * 4 + 0][ar] = a.x; As[ac4 * 4 + 1][ar] = a.y;
    As[ac4 * 4 + 2][ar] = a.z; As[ac4 * 4 + 3][ar] = a.w;
    *(float4*)&Bs[bk][bn4 * 4] =
        *(const float4*)(W + (size_t)(k0 + bk) * DD + col0 + bn4 * 4);
    __syncthreads();
#pragma unroll
    for (int kk = 0; kk < 16; ++kk) {
      float4 a4 = *(const float4*)&As[kk][ty * 4];
      float4 b4 = *(const float4*)&Bs[kk][tx * 4];
      float av[4] = {a4.x, a4.y, a4.z, a4.w};
      float bv[4] = {b4.x, b4.y, b4.z, b4.w};
#pragma unroll
      for (int i = 0; i < 4; ++i)
#pragma unroll
        for (int j = 0; j < 4; ++j) acc[i][j] += av[i] * bv[j];
    }
  }
  float4 bv4 = *(const float4*)(bias + col0 + tx * 4);
#pragma unroll
  for (int i = 0; i < 4; ++i) {
    int row = row0 + ty * 4 + i;
    float4 o;
    o.x = acc[i][0] + bv4.x; o.y = acc[i][1] + bv4.y;
    o.z = acc[i][2] + bv4.z; o.w = acc[i][3] + bv4.w;
    if (EPI == 1) {
      float4 rv = *(const float4*)(role_emb + (size_t)roles[row] * DD + col0 + tx * 4);
      o.x += rv.x; o.y += rv.y; o.z += rv.z; o.w += rv.w;
    }
    *(float4*)(C + (size_t)row * DD + col0 + tx * 4) = o;
  }
}

// ---------------- flash attention, f32, BR=BC=64 ----------------
__global__ __launch_bounds__(256) void attn_kernel(
    const float* __restrict__ Q, const float* __restrict__ Kk,
    const float* __restrict__ FS, const float* __restrict__ P,
    const unsigned char* __restrict__ mask8,
    const float* __restrict__ monf, const float* __restrict__ hubf,
    float* __restrict__ msg, float* __restrict__ entr,
    float* __restrict__ monr, float* __restrict__ hubr) {
  __shared__ float Qt[16][68], Ft[16][68], Kt[16][68], Gt[16][68];
  __shared__ float Et[64][68];
  __shared__ float Pt[64][256];
  int tid = threadIdx.x;
  int ty = tid >> 4, tx = tid & 15;
  int b = blockIdx.y;
  int r0 = blockIdx.x * 64;
  size_t base = (size_t)b * NN;
  const float* Qb = Q + base * DD;
  const float* Kb = Kk + base * DD;
  const float* Fb = FS + base * DD;
  const float* Pb = P + base * DD;

  float m[4], Zr[4], S1[4], Tm[4], Th[4];
  float Mac[4][16];
#pragma unroll
  for (int i = 0; i < 4; ++i) {
    m[i] = -1e30f; Zr[i] = 0.f; S1[i] = 0.f; Tm[i] = 0.f; Th[i] = 0.f;
#pragma unroll
    for (int dd = 0; dd < 16; ++dd) Mac[i][dd] = 0.f;
  }
  int ar = tid >> 2, ac4 = tid & 3;

  for (int c0 = 0; c0 < NN; c0 += 64) {
    float acc[4][4] = {};
    // S = (Q/16)·K^T + (0.5·FS)·FS^T   (both scalings are exact pow2 in f32)
    for (int k0 = 0; k0 < DD; k0 += 16) {
      __syncthreads();
      float4 q = *(const float4*)(Qb + (size_t)(r0 + ar) * DD + k0 + ac4 * 4);
      float4 f = *(const float4*)(Fb + (size_t)(r0 + ar) * DD + k0 + ac4 * 4);
      float4 kv = *(const float4*)(Kb + (size_t)(c0 + ar) * DD + k0 + ac4 * 4);
      float4 gg = *(const float4*)(Fb + (size_t)(c0 + ar) * DD + k0 + ac4 * 4);
      Qt[ac4 * 4 + 0][ar] = q.x * 0.0625f; Qt[ac4 * 4 + 1][ar] = q.y * 0.0625f;
      Qt[ac4 * 4 + 2][ar] = q.z * 0.0625f; Qt[ac4 * 4 + 3][ar] = q.w * 0.0625f;
      Ft[ac4 * 4 + 0][ar] = f.x * 0.5f; Ft[ac4 * 4 + 1][ar] = f.y * 0.5f;
      Ft[ac4 * 4 + 2][ar] = f.z * 0.5f; Ft[ac4 * 4 + 3][ar] = f.w * 0.5f;
      Kt[ac4 * 4 + 0][ar] = kv.x; Kt[ac4 * 4 + 1][ar] = kv.y;
      Kt[ac4 * 4 + 2][ar] = kv.z; Kt[ac4 * 4 + 3][ar] = kv.w;
      Gt[ac4 * 4 + 0][ar] = gg.x; Gt[ac4 * 4 + 1][ar] = gg.y;
      Gt[ac4 * 4 + 2][ar] = gg.z; Gt[ac4 * 4 + 3][ar] = gg.w;
      __syncthreads();
#pragma unroll
      for (int kk = 0; kk < 16; ++kk) {
        float4 a4 = *(const float4*)&Qt[kk][ty * 4];
        float4 f4 = *(const float4*)&Ft[kk][ty * 4];
        float4 k4 = *(const float4*)&Kt[kk][tx * 4];
        float4 g4 = *(const float4*)&Gt[kk][tx * 4];
        float avq[4] = {a4.x, a4.y, a4.z, a4.w};
        float avf[4] = {f4.x, f4.y, f4.z, f4.w};
        float bvk[4] = {k4.x, k4.y, k4.z, k4.w};
        float bvg[4] = {g4.x, g4.y, g4.z, g4.w};
#pragma unroll
        for (int i = 0; i < 4; ++i)
#pragma unroll
          for (int j = 0; j < 4; ++j)
            acc[i][j] += avq[i] * bvk[j] + avf[i] * bvg[j];
      }
    }
    // masked online softmax update (per row; row replicated over 16 lanes)
    float cm[4], cmo[4], chu[4];
#pragma unroll
    for (int j = 0; j < 4; ++j) {
      int cj = c0 + tx * 4 + j;
      cm[j] = (float)mask8[base + cj];
      cmo[j] = monf[cj];
      chu[j] = hubf[cj];
    }
#pragma unroll
    for (int i = 0; i < 4; ++i) {
      float l[4];
#pragma unroll
      for (int j = 0; j < 4; ++j) l[j] = (cm[j] != 0.0f) ? acc[i][j] : -1e30f;
      float mt = fmaxf(fmaxf(l[0], l[1]), fmaxf(l[2], l[3]));
#pragma unroll
      for (int mk = 1; mk < 16; mk <<= 1) mt = fmaxf(mt, __shfl_xor(mt, mk, 16));
      float mnew = fmaxf(m[i], mt);
      float ci = expf(m[i] - mnew);
      float e[4], zl = 0.f, s1l = 0.f, tml = 0.f, thl = 0.f;
#pragma unroll
      for (int j = 0; j < 4; ++j) {
        e[j] = expf(l[j] - mnew);
        zl += e[j];
        s1l += e[j] * (l[j] - mnew);
        tml += e[j] * cmo[j];
        thl += e[j] * chu[j];
      }
#pragma unroll
      for (int mk = 1; mk < 16; mk <<= 1) {
        zl += __shfl_xor(zl, mk, 16);
        s1l += __shfl_xor(s1l, mk, 16);
        tml += __shfl_xor(tml, mk, 16);
        thl += __shfl_xor(thl, mk, 16);
      }
      S1[i] = ci * (S1[i] + (m[i] - mnew) * Zr[i]) + s1l;
      Zr[i] = ci * Zr[i] + zl;
      Tm[i] = ci * Tm[i] + tml;
      Th[i] = ci * Th[i] + thl;
#pragma unroll
      for (int dd = 0; dd < 16; ++dd) Mac[i][dd] *= ci;
      m[i] = mnew;
#pragma unroll
      for (int j = 0; j < 4; ++j) Et[ty * 4 + i][tx * 4 + j] = e[j];
    }
    __syncthreads();
    {  // stage payload tile [64 x 256]
      int pj = tid >> 2;
      int pd0 = (tid & 3) * 4;
#pragma unroll
      for (int rep = 0; rep < 16; ++rep) {
        int d = pd0 + rep * 16;
        *(float4*)&Pt[pj][d] = *(const float4*)(Pb + (size_t)(c0 + pj) * DD + d);
      }
    }
    __syncthreads();
    // PV: Mac[i][dd] += sum_j E[row][j] * P[j][tx + dd*16]
#pragma unroll 4
    for (int j = 0; j < 64; ++j) {
      float ev[4];
#pragma unroll
      for (int i = 0; i < 4; ++i) ev[i] = Et[ty * 4 + i][j];
#pragma unroll
      for (int dd = 0; dd < 16; ++dd) {
        float pv = Pt[j][tx + dd * 16];
#pragma unroll
        for (int i = 0; i < 4; ++i) Mac[i][dd] += ev[i] * pv;
      }
    }
  }
  // finalize rows
#pragma unroll
  for (int i = 0; i < 4; ++i) {
    int row = r0 + ty * 4 + i;
    int valid = (mask8[base + row] != 0);
    float invZ = valid ? (1.0f / Zr[i]) : 0.0f;
#pragma unroll
    for (int dd = 0; dd < 16; ++dd)
      msg[(base + row) * DD + tx + dd * 16] = Mac[i][dd] * invZ;
    if (tx == 0) {
      entr[base + row] = valid ? (logf(Zr[i]) - S1[i] / Zr[i]) : 0.0f;
      monr[base + row] = valid ? (Tm[i] / Zr[i]) : 0.0f;
      hubr[base + row] = valid ? (Th[i] / Zr[i]) : 0.0f;
    }
  }
}

// ---------------- gate GEMM: gm = sigmoid([x|msg]@Wg + bg) * msg ----------------
__global__ __launch_bounds__(256) void gemm_gate_kernel(
    const float* __restrict__ x, const float* __restrict__ msg,
    const float* __restrict__ Wg, const float* __restrict__ bg,
    float* __restrict__ gm) {
  __shared__ float As[16][68];
  __shared__ float Bs[16][68];
  int tid = threadIdx.x;
  int ty = tid >> 4, tx = tid & 15;
  int row0 = blockIdx.y * 64, col0 = blockIdx.x * 64;
  int ar = tid >> 2, ac4 = tid & 3;
  int bk = tid >> 4, bn4 = tid & 15;
  float acc[4][4] = {};
  for (int k0 = 0; k0 < 2 * DD; k0 += 16) {
    const float* Asrc = (k0 < DD) ? x : msg;
    int kof = k0 & (DD - 1);
    __syncthreads();
    float4 a = *(const float4*)(Asrc + (size_t)(row0 + ar) * DD + kof + ac4 * 4);
    As[ac4 * 4 + 0][ar] = a.x; As[ac4 * 4 + 1][ar] = a.y;
    As[ac4 * 4 + 2][ar] = a.z; As[ac4 * 4 + 3][ar] = a.w;
    *(float4*)&Bs[bk][bn4 * 4] =
        *(const float4*)(Wg + (size_t)(k0 + bk) * DD + col0 + bn4 * 4);
    __syncthreads();
#pragma unroll
    for (int kk = 0; kk < 16; ++kk) {
      float4 a4 = *(const float4*)&As[kk][ty * 4];
      float4 b4 = *(const float4*)&Bs[kk][tx * 4];
      float av[4] = {a4.x, a4.y, a4.z, a4.w};
      float bv[4] = {b4.x, b4.y, b4.z, b4.w};
#pragma unroll
      for (int i = 0; i < 4; ++i)
#pragma unroll
        for (int j = 0; j < 4; ++j) acc[i][j] += av[i] * bv[j];
    }
  }
  float4 bgv = *(const float4*)(bg + col0 + tx * 4);
#pragma unroll
  for (int i = 0; i < 4; ++i) {
    int row = row0 + ty * 4 + i;
    float4 mv = *(const float4*)(msg + (size_t)row * DD + col0 + tx * 4);
    float4 o;
    o.x = (1.0f / (1.0f + expf(-(acc[i][0] + bgv.x)))) * mv.x;
    o.y = (1.0f / (1.0f + expf(-(acc[i][1] + bgv.y)))) * mv.y;
    o.z = (1.0f / (1.0f + expf(-(acc[i][2] + bgv.z)))) * mv.z;
    o.w = (1.0f / (1.0f + expf(-(acc[i][3] + bgv.w)))) * mv.w;
    *(float4*)(gm + (size_t)row * DD + col0 + tx * 4) = o;
  }
}

// ---------------- out GEMM: out = x + gm@Wo + bo ----------------
__global__ __launch_bounds__(256) void gemm_out_kernel(
    const float* __restrict__ gm, const float* __restrict__ Wo,
    const float* __restrict__ bo, const float* __restrict__ x,
    float* __restrict__ out) {
  __shared__ float As[16][68];
  __shared__ float Bs[16][68];
  int tid = threadIdx.x;
  int ty = tid >> 4, tx = tid & 15;
  int row0 = blockIdx.y * 64, col0 = blockIdx.x * 64;
  int ar = tid >> 2, ac4 = tid & 3;
  int bk = tid >> 4, bn4 = tid & 15;
  float acc[4][4] = {};
  for (int k0 = 0; k0 < DD; k0 += 16) {
    __syncthreads();
    float4 a = *(const float4*)(gm + (size_t)(row0 + ar) * DD + k0 + ac4 * 4);
    As[ac4 * 4 + 0][ar] = a.x; As[ac4 * 4 + 1][ar] = a.y;
    As[ac4 * 4 + 2][ar] = a.z; As[ac4 * 4 + 3][ar] = a.w;
    *(float4*)&Bs[bk][bn4 * 4] =
        *(const float4*)(Wo + (size_t)(k0 + bk) * DD + col0 + bn4 * 4);
    __syncthreads();
#pragma unroll
    for (int kk = 0; kk < 16; ++kk) {
      float4 a4 = *(const float4*)&As[kk][ty * 4];
      float4 b4 = *(const float4*)&Bs[kk][tx * 4];
      float av[4] = {a4.x, a4.y, a4.z, a4.w};
      float bv[4] = {b4.x, b4.y, b4.z, b4.w};
#pragma unroll
      for (int i = 0; i < 4; ++i)
#pragma unroll
        for (int j = 0; j < 4; ++j) acc[i][j] += av[i] * bv[j];
    }
  }
  float4 bov = *(const float4*)(bo + col0 + tx * 4);
#pragma unroll
  for (int i = 0; i < 4; ++i) {
    int row = row0 + ty * 4 + i;
    float4 xv = *(const float4*)(x + (size_t)row * DD + col0 + tx * 4);
    float4 o;
    o.x = xv.x + acc[i][0] + bov.x;
    o.y = xv.y + acc[i][1] + bov.y;
    o.z = xv.z + acc[i][2] + bov.z;
    o.w = xv.w + acc[i][3] + bov.w;
    *(float4*)(out + (size_t)row * DD + col0 + tx * 4) = o;
  }
}

// ---------------- final scalar reduction ----------------
__device__ __forceinline__ float block_sum(float v, float* sh) {
  __syncthreads();
  sh[threadIdx.x] = v;
  __syncthreads();
  for (int s = 128; s > 0; s >>= 1) {
    if ((int)threadIdx.x < s) sh[threadIdx.x] += sh[threadIdx.x + s];
    __syncthreads();
  }
  return sh[0];
}

__global__ __launch_bounds__(256) void reduce_kernel(
    const float* __restrict__ entr, const float* __restrict__ monr,
    const float* __restrict__ hubr, const float* __restrict__ monf,
    const float* __restrict__ hubf, float* __restrict__ out3) {
  __shared__ float sh[256];
  float es = 0.f, ms = 0.f, hs = 0.f, cmf = 0.f, chf = 0.f;
  for (int i = threadIdx.x; i < MTOK; i += 256) {
    es += entr[i]; ms += monr[i]; hs += hubr[i];
  }
  for (int j = threadIdx.x; j < NN; j += 256) { cmf += monf[j]; chf += hubf[j]; }
  float esum = block_sum(es, sh);
  float msum = block_sum(ms, sh);
  float hsum = block_sum(hs, sh);
  float cmsum = block_sum(cmf, sh);
  float chsum = block_sum(chf, sh);
  if (threadIdx.x == 0) {
    out3[0] = esum / 16384.0f;
    out3[1] = (cmsum > 0.f) ? (msum / (cmsum * 16384.0f)) : 0.0f;
    out3[2] = (chsum > 0.f) ? (hsum / (chsum * 16384.0f)) : 0.0f;
  }
}

extern "C" void kernel_launch(void* const* d_in, const int* in_sizes, int n_in,
                              void* d_out, int out_size, void* d_ws, size_t ws_size,
                              hipStream_t stream) {
  const float* x = (const float*)d_in[0];
  const int* roles = (const int*)d_in[1];
  const void* mraw = d_in[2];
  const float* gamma = (const float*)d_in[3];
  const float* beta = (const float*)d_in[4];
  const float* remb = (const float*)d_in[5];
  const float* Wq = (const float*)d_in[6];
  const float* bq = (const float*)d_in[7];
  const float* Wk = (const float*)d_in[8];
  const float* bk = (const float*)d_in[9];
  const float* Ws = (const float*)d_in[10];
  const float* bs = (const float*)d_in[11];
  const float* Wp = (const float*)d_in[12];
  const float* bp = (const float*)d_in[13];
  const float* Wo = (const float*)d_in[14];
  const float* bo = (const float*)d_in[15];
  const float* Wg = (const float*)d_in[16];
  const float* bg = (const float*)d_in[17];

  float* ws = (float*)d_ws;
  float* normed = ws + OFF_NORMED;
  float* h = ws + OFF_H;
  float* Qm = ws + OFF_Q;
  float* Km = ws + OFF_K;
  float* FSm = ws + OFF_FS;
  float* Pm = ws + OFF_P;
  float* msg = ws + OFF_MSG;
  float* gm = ws + OFF_GM;
  float* entr = ws + OFF_ENT;
  float* monr = ws + OFF_MONR;
  float* hubr = ws + OFF_HUBR;
  float* monfp = ws + OFF_MONF;
  float* hubfp = ws + OFF_HUBF;
  unsigned char* mask8 = (unsigned char*)(ws + OFF_MASK);
  int* kind = (int*)(ws + OFF_KIND);
  float* out = (float*)d_out;

  detect_mask_kernel<<<1, 256, 0, stream>>>((const unsigned char*)mraw, kind);
  build_mask_kernel<<<64, 256, 0, stream>>>(mraw, roles, kind, mask8, monfp, hubfp);
  prep_kernel<<<4096, 256, 0, stream>>>(x, roles, gamma, beta, remb, normed, h);
  dim3 gg(4, 256);
  gemm256_kernel<0><<<gg, 256, 0, stream>>>(h, Wq, bq, Qm, nullptr, nullptr);
  gemm256_kernel<0><<<gg, 256, 0, stream>>>(h, Wk, bk, Km, nullptr, nullptr);
  gemm256_kernel<1><<<gg, 256, 0, stream>>>(h, Ws, bs, FSm, roles, remb);
  gemm256_kernel<0><<<gg, 256, 0, stream>>>(normed, Wp, bp, Pm, nullptr, nullptr);
  dim3 ga(32, 8);
  attn_kernel<<<ga, 256, 0, stream>>>(Qm, Km, FSm, Pm, mask8, monfp, hubfp,
                                      msg, entr, monr, hubr);
  gemm_gate_kernel<<<gg, 256, 0, stream>>>(x, msg, Wg, bg, gm);
  gemm_out_kernel<<<gg, 256, 0, stream>>>(gm, Wo, bo, x, out);
  reduce_kernel<<<1, 256, 0, stream>>>(entr, monr, hubr, monfp, hubfp,
                                       out + 4194304);
}

// Round 2
// 428.751 us; speedup vs baseline: 3.8160x; 3.8160x over previous
//
#include <hip/hip_runtime.h>
#include <math.h>

#define BB 8
#define NN 2048
#define DD 256
#define MTOK 16384

typedef __bf16 bf16x8 __attribute__((ext_vector_type(8)));
typedef __bf16 bf16x4 __attribute__((ext_vector_type(4)));
typedef float f32x4 __attribute__((ext_vector_type(4)));

#define MFMA16(a, b, c) __builtin_amdgcn_mfma_f32_16x16x32_bf16(a, b, c, 0, 0, 0)

// ---- workspace layout (float offsets) ----
#define OFF_NORMED 0ull
#define OFF_H      4194304ull
#define OFF_GROW   8388608ull    // bf16 [16384][512]  ([q/16 | fs*sqrt(.5)])
#define OFF_GCOL   12582912ull   // bf16 [16384][512]  ([k    | fs*sqrt(.5)])
#define OFF_PB     16777216ull   // bf16 [16384][256]
#define OFF_PT     18874368ull   // bf16 [8][256][2048]
#define OFF_MSG    OFF_NORMED    // msg overwrites normed (dead after P projection)
#define OFF_GM     OFF_H         // gate*msg overwrites h (dead after projections)
#define OFF_ENT    20971520ull
#define OFF_MONR   (OFF_ENT + 16384ull)
#define OFF_HUBR   (OFF_MONR + 16384ull)
#define OFF_MONF   (OFF_HUBR + 16384ull)
#define OFF_HUBF   (OFF_MONF + 2048ull)
#define OFF_MASK   (OFF_HUBF + 2048ull)   // 16384 bytes
#define OFF_KIND   (OFF_MASK + 4096ull)

__device__ __forceinline__ void gl_lds16(const void* g, void* l) {
  __builtin_amdgcn_global_load_lds(
      (const __attribute__((address_space(1))) unsigned int*)g,
      (__attribute__((address_space(3))) unsigned int*)l, 16, 0, 0);
}

// ---------------- mask dtype detection ----------------
__global__ __launch_bounds__(256) void detect_mask_kernel(
    const unsigned char* __restrict__ mraw, int* __restrict__ kind) {
  __shared__ int c0s, c1s;
  if (threadIdx.x == 0) { c0s = 0; c1s = 0; }
  __syncthreads();
  int c0 = 0, c1 = 0;
  for (int i = threadIdx.x; i < MTOK; i += 256) {
    int nz = (mraw[i] != 0) ? 1 : 0;
    if ((i & 3) == 0) c0 += nz; else c1 += nz;
  }
  atomicAdd(&c0s, c0);
  atomicAdd(&c1s, c1);
  __syncthreads();
  if (threadIdx.x == 0) {
    int k;
    if (c0s == 0) k = 2;
    else if (c1s == 0) k = 0;
    else k = 1;
    *kind = k;
  }
}

__global__ __launch_bounds__(256) void build_mask_kernel(
    const void* __restrict__ mraw, const int* __restrict__ roles,
    const int* __restrict__ kind, unsigned char* __restrict__ mask8,
    float* __restrict__ monf, float* __restrict__ hubf) {
  int t = blockIdx.x * 256 + threadIdx.x;
  if (t < MTOK) {
    int k = *kind;
    int v;
    if (k == 1)      v = (((const unsigned char*)mraw)[t] != 0);
    else if (k == 0) v = (((const int*)mraw)[t] != 0);
    else             v = (((const float*)mraw)[t] != 0.0f);
    mask8[t] = (unsigned char)v;
  }
  if (t < NN) {
    int mon = 0, hub = 0;
#pragma unroll
    for (int b = 0; b < BB; ++b) {
      int r = roles[b * NN + t];
      mon |= (r == 2) ? 1 : 0;
      hub |= (r == 1) ? 1 : 0;
    }
    monf[t] = (float)mon;
    hubf[t] = (float)hub;
  }
}

// ---------------- layernorm + role bias ----------------
__global__ __launch_bounds__(256) void prep_kernel(
    const float* __restrict__ x, const int* __restrict__ roles,
    const float* __restrict__ gamma, const float* __restrict__ beta,
    const float* __restrict__ role_emb,
    float* __restrict__ normed, float* __restrict__ h) {
  int t = blockIdx.x * 4 + (threadIdx.x >> 6);
  int lane = threadIdx.x & 63;
  size_t off = (size_t)t * DD + lane * 4;
  float4 xv = *(const float4*)(x + off);
  float s = xv.x + xv.y + xv.z + xv.w;
  float ss = xv.x * xv.x + xv.y * xv.y + xv.z * xv.z + xv.w * xv.w;
#pragma unroll
  for (int m = 1; m < 64; m <<= 1) {
    s += __shfl_xor(s, m, 64);
    ss += __shfl_xor(ss, m, 64);
  }
  float mu = s * (1.0f / 256.0f);
  float var = ss * (1.0f / 256.0f) - mu * mu;
  float inv = rsqrtf(var + 1e-5f);
  float4 g = *(const float4*)(gamma + lane * 4);
  float4 be = *(const float4*)(beta + lane * 4);
  float4 nv;
  nv.x = (xv.x - mu) * inv * g.x + be.x;
  nv.y = (xv.y - mu) * inv * g.y + be.y;
  nv.z = (xv.z - mu) * inv * g.z + be.z;
  nv.w = (xv.w - mu) * inv * g.w + be.w;
  *(float4*)(normed + off) = nv;
  int role = roles[t];
  float4 rb = *(const float4*)(role_emb + (size_t)role * DD + lane * 4);
  float4 hv;
  hv.x = nv.x + rb.x; hv.y = nv.y + rb.y; hv.z = nv.z + rb.z; hv.w = nv.w + rb.w;
  *(float4*)(h + off) = hv;
}

// -------- f32 GEMM -> bf16 output: dst[row][col] = bf16((A@W + b [+role])*scale)
// EPI 0: one dst. EPI 1: role add, two dsts (Grow+256 and Gcol+256).
template <int EPI>
__global__ __launch_bounds__(256) void gemm256b_kernel(
    const float* __restrict__ A, const float* __restrict__ W,
    const float* __restrict__ bias, const int* __restrict__ roles,
    const float* __restrict__ remb,
    __bf16* __restrict__ dst0, __bf16* __restrict__ dst1,
    long ldd, float scale) {
  __shared__ float As[16][68];
  __shared__ float Bs[16][68];
  int tid = threadIdx.x;
  int ty = tid >> 4, tx = tid & 15;
  int row0 = blockIdx.y * 64, col0 = blockIdx.x * 64;
  int ar = tid >> 2, ac4 = tid & 3;
  int bk = tid >> 4, bn4 = tid & 15;
  float acc[4][4] = {};
  for (int k0 = 0; k0 < DD; k0 += 16) {
    __syncthreads();
    float4 a = *(const float4*)(A + (size_t)(row0 + ar) * DD + k0 + ac4 * 4);
    As[ac4 * 4 + 0][ar] = a.x; As[ac4 * 4 + 1][ar] = a.y;
    As[ac4 * 4 + 2][ar] = a.z; As[ac4 * 4 + 3][ar] = a.w;
    *(float4*)&Bs[bk][bn4 * 4] =
        *(const float4*)(W + (size_t)(k0 + bk) * DD + col0 + bn4 * 4);
    __syncthreads();
#pragma unroll
    for (int kk = 0; kk < 16; ++kk) {
      float4 a4 = *(const float4*)&As[kk][ty * 4];
      float4 b4 = *(const float4*)&Bs[kk][tx * 4];
      float av[4] = {a4.x, a4.y, a4.z, a4.w};
      float bv[4] = {b4.x, b4.y, b4.z, b4.w};
#pragma unroll
      for (int i = 0; i < 4; ++i)
#pragma unroll
        for (int j = 0; j < 4; ++j) acc[i][j] += av[i] * bv[j];
    }
  }
  float4 bv4 = *(const float4*)(bias + col0 + tx * 4);
#pragma unroll
  for (int i = 0; i < 4; ++i) {
    int row = row0 + ty * 4 + i;
    float o[4];
    o[0] = acc[i][0] + bv4.x; o[1] = acc[i][1] + bv4.y;
    o[2] = acc[i][2] + bv4.z; o[3] = acc[i][3] + bv4.w;
    if (EPI == 1) {
      float4 rv = *(const float4*)(remb + (size_t)roles[row] * DD + col0 + tx * 4);
      o[0] += rv.x; o[1] += rv.y; o[2] += rv.z; o[3] += rv.w;
    }
    bf16x4 v;
#pragma unroll
    for (int j = 0; j < 4; ++j) v[j] = (__bf16)(o[j] * scale);
    *(bf16x4*)&dst0[(size_t)row * ldd + col0 + tx * 4] = v;
    if (EPI == 1)
      *(bf16x4*)&dst1[(size_t)row * ldd + col0 + tx * 4] = v;
  }
}

// -------- transpose Pb16 [b][token][256] -> PT [b][256][2048] --------
__global__ __launch_bounds__(256) void transpose_p_kernel(
    const __bf16* __restrict__ Pb, __bf16* __restrict__ PT) {
  __shared__ __bf16 T[64][72];
  int bx = blockIdx.x;   // token tile (32)
  int dt = blockIdx.y;   // d tile (4)
  int b = blockIdx.z;
  int t = threadIdx.x;
  int tr = t >> 3, tc = (t & 7) * 8;
#pragma unroll
  for (int p = 0; p < 2; ++p) {
    int tok = p * 32 + tr;
    bf16x8 v = *(const bf16x8*)&Pb[((size_t)(b * NN + bx * 64 + tok)) * DD + dt * 64 + tc];
    *(bf16x8*)&T[tok][tc] = v;
  }
  __syncthreads();
#pragma unroll
  for (int p = 0; p < 2; ++p) {
    int dr = p * 32 + tr;
    bf16x8 v;
#pragma unroll
    for (int q = 0; q < 8; ++q) v[q] = T[tc + q][dr];
    *(bf16x8*)&PT[((size_t)(b * DD + dt * 64 + dr)) * NN + bx * 64 + tc] = v;
  }
}

// ---------------- MFMA flash attention ----------------
// grid: 256 blocks 1-D (id = rowblock*8 + batch so XCD == batch), 256 threads.
// Block: 64 query rows; wave w owns rows w*16..w*16+16.
// Chunk BC=64 columns; S = Grow(rows) @ Gcol(cols)^T over K=512 (bf16 MFMA).
__global__ __launch_bounds__(256) void attn_kernel(
    const __bf16* __restrict__ Grow, const __bf16* __restrict__ Gcol,
    const __bf16* __restrict__ PT,
    const unsigned char* __restrict__ mask8,
    const float* __restrict__ monf, const float* __restrict__ hubf,
    float* __restrict__ msg, float* __restrict__ entr,
    float* __restrict__ monr, float* __restrict__ hubr) {
  __shared__ __align__(16) unsigned char GcS[65536];   // [64 tok][1024B] swizzled
  __shared__ __align__(16) unsigned char PtS[32768];   // [256 d][128B]   swizzled
  __shared__ float Elds[4 * 16 * 68];                  // per-wave E tile f32

  int tid = threadIdx.x;
  int w = tid >> 6;
  int lane = tid & 63;
  int ln15 = lane & 15;
  int lq = lane >> 4;           // 0..3
  int id = blockIdx.x;
  int b = id & 7;
  int r0 = (id >> 3) * 64;
  size_t base = (size_t)b * NN;

  // ---- load A-fragments for this wave's 16 rows: Grow[r0+w*16+ln15][k] ----
  bf16x8 Af[16];
  {
    const __bf16* gr = Grow + ((size_t)(base + r0 + w * 16 + ln15)) * 512 + lq * 8;
#pragma unroll
    for (int kk = 0; kk < 16; ++kk) Af[kk] = *(const bf16x8*)(gr + kk * 32);
  }

  float m[4], Zr[4], S1[4], Tm[4], Th[4];
  f32x4 macc[16];
#pragma unroll
  for (int r = 0; r < 4; ++r) { m[r] = -1e30f; Zr[r] = 0.f; S1[r] = 0.f; Tm[r] = 0.f; Th[r] = 0.f; }
#pragma unroll
  for (int nt = 0; nt < 16; ++nt) macc[nt] = (f32x4){0.f, 0.f, 0.f, 0.f};

  float* Ew = Elds + w * (16 * 68);

  for (int c0 = 0; c0 < NN; c0 += 64) {
    __syncthreads();   // previous PV reads done before restage
    // ---- stage Gcol tile: 64 rows x 1024B, 16 rows per wave ----
    {
      const unsigned char* gbase = (const unsigned char*)Gcol + ((size_t)(base + c0)) * 1024;
#pragma unroll
      for (int i = 0; i < 16; ++i) {
        int r = w * 16 + i;
        int srcb = (lane * 16) ^ ((r & 7) << 4);
        gl_lds16(gbase + (size_t)r * 1024 + srcb, GcS + r * 1024);
      }
    }
    // ---- stage PT tile: 256 d-rows x 128B, 8 KB per wave ----
    {
      const unsigned char* pbase = (const unsigned char*)PT + ((size_t)b * DD) * (NN * 2) + (size_t)c0 * 2;
#pragma unroll
      for (int i = 0; i < 8; ++i) {
        int ii = w * 8 + i;
        int drow = ii * 8 + (lane >> 3);
        int byte_in = (lane & 7) * 16;
        int srcb = byte_in ^ ((drow & 7) << 4);
        gl_lds16(pbase + (size_t)drow * (NN * 2) + srcb, PtS + ii * 1024);
      }
    }
    __syncthreads();   // staging complete

    // ---- S phase: 4 col-tiles, K=512 ----
    f32x4 sa[4];
#pragma unroll
    for (int jt = 0; jt < 4; ++jt) sa[jt] = (f32x4){0.f, 0.f, 0.f, 0.f};
#pragma unroll
    for (int kk = 0; kk < 16; ++kk) {
#pragma unroll
      for (int jt = 0; jt < 4; ++jt) {
        int n = jt * 16 + ln15;
        int byteoff = ((lq * 16) + kk * 64) ^ ((n & 7) << 4);
        bf16x8 bv = *(const bf16x8*)(GcS + n * 1024 + byteoff);
        sa[jt] = MFMA16(Af[kk], bv, sa[jt]);
      }
    }

    // ---- masked online softmax ----
    float cmask[4], cmon[4], chub[4];
#pragma unroll
    for (int jt = 0; jt < 4; ++jt) {
      int cg = c0 + jt * 16 + ln15;
      cmask[jt] = (float)mask8[base + cg];
      cmon[jt] = monf[cg];
      chub[jt] = hubf[cg];
    }
#pragma unroll
    for (int r = 0; r < 4; ++r) {
      float l[4];
#pragma unroll
      for (int jt = 0; jt < 4; ++jt)
        l[jt] = (cmask[jt] != 0.0f) ? sa[jt][r] : -1e30f;
      float mt = fmaxf(fmaxf(l[0], l[1]), fmaxf(l[2], l[3]));
#pragma unroll
      for (int mk = 1; mk < 16; mk <<= 1) mt = fmaxf(mt, __shfl_xor(mt, mk, 16));
      float mnew = fmaxf(m[r], mt);
      float ci = __expf(m[r] - mnew);
      float e[4], zl = 0.f, s1l = 0.f, tml = 0.f, thl = 0.f;
#pragma unroll
      for (int jt = 0; jt < 4; ++jt) {
        float ee = (cmask[jt] != 0.0f) ? __expf(l[jt] - mnew) : 0.0f;
        e[jt] = ee;
        zl += ee;
        s1l += ee * (l[jt] - mnew);
        tml += ee * cmon[jt];
        thl += ee * chub[jt];
      }
#pragma unroll
      for (int mk = 1; mk < 16; mk <<= 1) {
        zl += __shfl_xor(zl, mk, 16);
        s1l += __shfl_xor(s1l, mk, 16);
        tml += __shfl_xor(tml, mk, 16);
        thl += __shfl_xor(thl, mk, 16);
      }
      S1[r] = ci * (S1[r] + (m[r] - mnew) * Zr[r]) + s1l;
      Zr[r] = ci * Zr[r] + zl;
      Tm[r] = ci * Tm[r] + tml;
      Th[r] = ci * Th[r] + thl;
      m[r] = mnew;
#pragma unroll
      for (int nt = 0; nt < 16; ++nt) macc[nt][r] *= ci;
      // write E (f32) in C layout: row = lq*4+r, col = jt*16+ln15
#pragma unroll
      for (int jt = 0; jt < 4; ++jt)
        Ew[(lq * 4 + r) * 68 + jt * 16 + ln15] = e[jt];
    }

    // ---- PV: macc += E @ P^T-tile ----
#pragma unroll
    for (int ks = 0; ks < 2; ++ks) {
      int ek = lq * 8 + ks * 32;
      f32x4 e0 = *(const f32x4*)(Ew + ln15 * 68 + ek);
      f32x4 e1 = *(const f32x4*)(Ew + ln15 * 68 + ek + 4);
      bf16x8 ef;
#pragma unroll
      for (int q = 0; q < 4; ++q) { ef[q] = (__bf16)e0[q]; ef[q + 4] = (__bf16)e1[q]; }
#pragma unroll
      for (int nt = 0; nt < 16; ++nt) {
        int drow = nt * 16 + ln15;
        int byteoff = (lq * 16 + ks * 64) ^ ((drow & 7) << 4);
        bf16x8 pv = *(const bf16x8*)(PtS + drow * 128 + byteoff);
        macc[nt] = MFMA16(ef, pv, macc[nt]);
      }
    }
  }

  // ---- finalize ----
#pragma unroll
  for (int r = 0; r < 4; ++r) {
    int grow = r0 + w * 16 + lq * 4 + r;
    int valid = (mask8[base + grow] != 0);
    float invZ = valid ? (1.0f / Zr[r]) : 0.0f;
#pragma unroll
    for (int nt = 0; nt < 16; ++nt)
      msg[(base + grow) * DD + nt * 16 + ln15] = macc[nt][r] * invZ;
    if (ln15 == 0) {
      entr[base + grow] = valid ? (logf(Zr[r]) - S1[r] / Zr[r]) : 0.0f;
      monr[base + grow] = valid ? (Tm[r] / Zr[r]) : 0.0f;
      hubr[base + grow] = valid ? (Th[r] / Zr[r]) : 0.0f;
    }
  }
}

// ---------------- gate GEMM: gm = sigmoid([x|msg]@Wg + bg) * msg ----------------
__global__ __launch_bounds__(256) void gemm_gate_kernel(
    const float* __restrict__ x, const float* __restrict__ msg,
    const float* __restrict__ Wg, const float* __restrict__ bg,
    float* __restrict__ gm) {
  __shared__ float As[16][68];
  __shared__ float Bs[16][68];
  int tid = threadIdx.x;
  int ty = tid >> 4, tx = tid & 15;
  int row0 = blockIdx.y * 64, col0 = blockIdx.x * 64;
  int ar = tid >> 2, ac4 = tid & 3;
  int bk = tid >> 4, bn4 = tid & 15;
  float acc[4][4] = {};
  for (int k0 = 0; k0 < 2 * DD; k0 += 16) {
    const float* Asrc = (k0 < DD) ? x : msg;
    int kof = k0 & (DD - 1);
    __syncthreads();
    float4 a = *(const float4*)(Asrc + (size_t)(row0 + ar) * DD + kof + ac4 * 4);
    As[ac4 * 4 + 0][ar] = a.x; As[ac4 * 4 + 1][ar] = a.y;
    As[ac4 * 4 + 2][ar] = a.z; As[ac4 * 4 + 3][ar] = a.w;
    *(float4*)&Bs[bk][bn4 * 4] =
        *(const float4*)(Wg + (size_t)(k0 + bk) * DD + col0 + bn4 * 4);
    __syncthreads();
#pragma unroll
    for (int kk = 0; kk < 16; ++kk) {
      float4 a4 = *(const float4*)&As[kk][ty * 4];
      float4 b4 = *(const float4*)&Bs[kk][tx * 4];
      float av[4] = {a4.x, a4.y, a4.z, a4.w};
      float bv[4] = {b4.x, b4.y, b4.z, b4.w};
#pragma unroll
      for (int i = 0; i < 4; ++i)
#pragma unroll
        for (int j = 0; j < 4; ++j) acc[i][j] += av[i] * bv[j];
    }
  }
  float4 bgv = *(const float4*)(bg + col0 + tx * 4);
#pragma unroll
  for (int i = 0; i < 4; ++i) {
    int row = row0 + ty * 4 + i;
    float4 mv = *(const float4*)(msg + (size_t)row * DD + col0 + tx * 4);
    float4 o;
    o.x = (1.0f / (1.0f + __expf(-(acc[i][0] + bgv.x)))) * mv.x;
    o.y = (1.0f / (1.0f + __expf(-(acc[i][1] + bgv.y)))) * mv.y;
    o.z = (1.0f / (1.0f + __expf(-(acc[i][2] + bgv.z)))) * mv.z;
    o.w = (1.0f / (1.0f + __expf(-(acc[i][3] + bgv.w)))) * mv.w;
    *(float4*)(gm + (size_t)row * DD + col0 + tx * 4) = o;
  }
}

// ---------------- out GEMM: out = x + gm@Wo + bo ----------------
__global__ __launch_bounds__(256) void gemm_out_kernel(
    const float* __restrict__ gm, const float* __restrict__ Wo,
    const float* __restrict__ bo, const float* __restrict__ x,
    float* __restrict__ out) {
  __shared__ float As[16][68];
  __shared__ float Bs[16][68];
  int tid = threadIdx.x;
  int ty = tid >> 4, tx = tid & 15;
  int row0 = blockIdx.y * 64, col0 = blockIdx.x * 64;
  int ar = tid >> 2, ac4 = tid & 3;
  int bk = tid >> 4, bn4 = tid & 15;
  float acc[4][4] = {};
  for (int k0 = 0; k0 < DD; k0 += 16) {
    __syncthreads();
    float4 a = *(const float4*)(gm + (size_t)(row0 + ar) * DD + k0 + ac4 * 4);
    As[ac4 * 4 + 0][ar] = a.x; As[ac4 * 4 + 1][ar] = a.y;
    As[ac4 * 4 + 2][ar] = a.z; As[ac4 * 4 + 3][ar] = a.w;
    *(float4*)&Bs[bk][bn4 * 4] =
        *(const float4*)(Wo + (size_t)(k0 + bk) * DD + col0 + bn4 * 4);
    __syncthreads();
#pragma unroll
    for (int kk = 0; kk < 16; ++kk) {
      float4 a4 = *(const float4*)&As[kk][ty * 4];
      float4 b4 = *(const float4*)&Bs[kk][tx * 4];
      float av[4] = {a4.x, a4.y, a4.z, a4.w};
      float bv[4] = {b4.x, b4.y, b4.z, b4.w};
#pragma unroll
      for (int i = 0; i < 4; ++i)
#pragma unroll
        for (int j = 0; j < 4; ++j) acc[i][j] += av[i] * bv[j];
    }
  }
  float4 bov = *(const float4*)(bo + col0 + tx * 4);
#pragma unroll
  for (int i = 0; i < 4; ++i) {
    int row = row0 + ty * 4 + i;
    float4 xv = *(const float4*)(x + (size_t)row * DD + col0 + tx * 4);
    float4 o;
    o.x = xv.x + acc[i][0] + bov.x;
    o.y = xv.y + acc[i][1] + bov.y;
    o.z = xv.z + acc[i][2] + bov.z;
    o.w = xv.w + acc[i][3] + bov.w;
    *(float4*)(out + (size_t)row * DD + col0 + tx * 4) = o;
  }
}

// ---------------- final scalar reduction ----------------
__device__ __forceinline__ float block_sum(float v, float* sh) {
  __syncthreads();
  sh[threadIdx.x] = v;
  __syncthreads();
  for (int s = 128; s > 0; s >>= 1) {
    if ((int)threadIdx.x < s) sh[threadIdx.x] += sh[threadIdx.x + s];
    __syncthreads();
  }
  return sh[0];
}

__global__ __launch_bounds__(256) void reduce_kernel(
    const float* __restrict__ entr, const float* __restrict__ monr,
    const float* __restrict__ hubr, const float* __restrict__ monf,
    const float* __restrict__ hubf, float* __restrict__ out3) {
  __shared__ float sh[256];
  float es = 0.f, ms = 0.f, hs = 0.f, cmf = 0.f, chf = 0.f;
  for (int i = threadIdx.x; i < MTOK; i += 256) {
    es += entr[i]; ms += monr[i]; hs += hubr[i];
  }
  for (int j = threadIdx.x; j < NN; j += 256) { cmf += monf[j]; chf += hubf[j]; }
  float esum = block_sum(es, sh);
  float msum = block_sum(ms, sh);
  float hsum = block_sum(hs, sh);
  float cmsum = block_sum(cmf, sh);
  float chsum = block_sum(chf, sh);
  if (threadIdx.x == 0) {
    out3[0] = esum / 16384.0f;
    out3[1] = (cmsum > 0.f) ? (msum / (cmsum * 16384.0f)) : 0.0f;
    out3[2] = (chsum > 0.f) ? (hsum / (chsum * 16384.0f)) : 0.0f;
  }
}

extern "C" void kernel_launch(void* const* d_in, const int* in_sizes, int n_in,
                              void* d_out, int out_size, void* d_ws, size_t ws_size,
                              hipStream_t stream) {
  const float* x = (const float*)d_in[0];
  const int* roles = (const int*)d_in[1];
  const void* mraw = d_in[2];
  const float* gamma = (const float*)d_in[3];
  const float* beta = (const float*)d_in[4];
  const float* remb = (const float*)d_in[5];
  const float* Wq = (const float*)d_in[6];
  const float* bq = (const float*)d_in[7];
  const float* Wk = (const float*)d_in[8];
  const float* bk = (const float*)d_in[9];
  const float* Ws = (const float*)d_in[10];
  const float* bs = (const float*)d_in[11];
  const float* Wp = (const float*)d_in[12];
  const float* bp = (const float*)d_in[13];
  const float* Wo = (const float*)d_in[14];
  const float* bo = (const float*)d_in[15];
  const float* Wg = (const float*)d_in[16];
  const float* bg = (const float*)d_in[17];

  float* ws = (float*)d_ws;
  float* normed = ws + OFF_NORMED;
  float* h = ws + OFF_H;
  __bf16* Grow = (__bf16*)(ws + OFF_GROW);
  __bf16* Gcol = (__bf16*)(ws + OFF_GCOL);
  __bf16* Pb16 = (__bf16*)(ws + OFF_PB);
  __bf16* PT = (__bf16*)(ws + OFF_PT);
  float* msg = ws + OFF_MSG;
  float* gm = ws + OFF_GM;
  float* entr = ws + OFF_ENT;
  float* monr = ws + OFF_MONR;
  float* hubr = ws + OFF_HUBR;
  float* monfp = ws + OFF_MONF;
  float* hubfp = ws + OFF_HUBF;
  unsigned char* mask8 = (unsigned char*)(ws + OFF_MASK);
  int* kind = (int*)(ws + OFF_KIND);
  float* out = (float*)d_out;

  detect_mask_kernel<<<1, 256, 0, stream>>>((const unsigned char*)mraw, kind);
  build_mask_kernel<<<64, 256, 0, stream>>>(mraw, roles, kind, mask8, monfp, hubfp);
  prep_kernel<<<4096, 256, 0, stream>>>(x, roles, gamma, beta, remb, normed, h);
  dim3 gg(4, 256);
  // q -> Grow[:, 0:256], scale 1/16
  gemm256b_kernel<0><<<gg, 256, 0, stream>>>(h, Wq, bq, nullptr, nullptr,
                                             Grow, nullptr, 512, 0.0625f);
  // k -> Gcol[:, 0:256]
  gemm256b_kernel<0><<<gg, 256, 0, stream>>>(h, Wk, bk, nullptr, nullptr,
                                             Gcol, nullptr, 512, 1.0f);
  // fs -> Grow[:, 256:512] and Gcol[:, 256:512], scale sqrt(0.5)
  gemm256b_kernel<1><<<gg, 256, 0, stream>>>(h, Ws, bs, roles, remb,
                                             Grow + 256, Gcol + 256, 512,
                                             0.70710678118f);
  // payload -> Pb16
  gemm256b_kernel<0><<<gg, 256, 0, stream>>>(normed, Wp, bp, nullptr, nullptr,
                                             Pb16, nullptr, 256, 1.0f);
  transpose_p_kernel<<<dim3(32, 4, 8), 256, 0, stream>>>(Pb16, PT);
  attn_kernel<<<256, 256, 0, stream>>>(Grow, Gcol, PT, mask8, monfp, hubfp,
                                       msg, entr, monr, hubr);
  gemm_gate_kernel<<<gg, 256, 0, stream>>>(x, msg, Wg, bg, gm);
  gemm_out_kernel<<<gg, 256, 0, stream>>>(gm, Wo, bo, x, out);
  reduce_kernel<<<1, 256, 0, stream>>>(entr, monr, hubr, monfp, hubfp,
                                       out + 4194304);
}

// Round 3
// 231.446 us; speedup vs baseline: 7.0691x; 1.8525x over previous
//
#include <hip/hip_runtime.h>
#include <math.h>

#define BB 8
#define NN 2048
#define DD 256
#define MTOK 16384

typedef __bf16 bf16x8 __attribute__((ext_vector_type(8)));
typedef __bf16 bf16x4 __attribute__((ext_vector_type(4)));
typedef float f32x4 __attribute__((ext_vector_type(4)));

#define MFMA16(a, b, c) __builtin_amdgcn_mfma_f32_16x16x32_bf16(a, b, c, 0, 0, 0)

// ---- workspace layout (float offsets) ----
#define OFF_X16    0ull          // bf16 [16384][256]
#define OFF_N16    2097152ull    // bf16 [16384][256]
#define OFF_H16    4194304ull    // bf16 [16384][256]
#define OFF_PB     6291456ull    // bf16 [16384][256]
#define OFF_GROW   8388608ull    // bf16 [16384][512]  ([q/16 | fs*sqrt(.5)])
#define OFF_GCOL   12582912ull   // bf16 [16384][512]  ([k    | fs*sqrt(.5)])
#define OFF_PTE    16777216ull   // bf16 [8][272][2048]
#define OFF_WT     19005440ull   // bf16: WTq,WTk,WTs,WTp @65536 ea; WTg(131072); WTo
#define OFF_STAT   19234816ull   // f32 [2][16384][6]
#define OFF_MSGP1  19431424ull   // f32 [16384][256]
#define OFF_ENT    23625728ull
#define OFF_MONR   23642112ull
#define OFF_HUBR   23658496ull
#define OFF_MONF   23674880ull
#define OFF_HUBF   23676928ull
#define OFF_MASK   23678976ull   // 16384 bytes
#define OFF_KIND   23683072ull
// aliases (dead-region reuse):
#define OFF_MSGP0  OFF_N16       // f32 [16384][256] over N16+H16 (dead after projections)
#define OFF_MSG16  OFF_PTE       // bf16 [16384][256] over PTE (dead after attn)
#define OFF_GM16   OFF_GROW      // bf16 [16384][256] over GROW (dead after attn)

__device__ __forceinline__ void gl_lds16(const void* g, void* l) {
  __builtin_amdgcn_global_load_lds(
      (const __attribute__((address_space(1))) unsigned int*)g,
      (__attribute__((address_space(3))) unsigned int*)l, 16, 0, 0);
}

// ---------------- mask dtype detection ----------------
__global__ __launch_bounds__(256) void detect_mask_kernel(
    const unsigned char* __restrict__ mraw, int* __restrict__ kind) {
  __shared__ int c0s, c1s;
  if (threadIdx.x == 0) { c0s = 0; c1s = 0; }
  __syncthreads();
  int c0 = 0, c1 = 0;
  for (int i = threadIdx.x; i < MTOK; i += 256) {
    int nz = (mraw[i] != 0) ? 1 : 0;
    if ((i & 3) == 0) c0 += nz; else c1 += nz;
  }
  atomicAdd(&c0s, c0);
  atomicAdd(&c1s, c1);
  __syncthreads();
  if (threadIdx.x == 0) {
    int k;
    if (c0s == 0) k = 2;
    else if (c1s == 0) k = 0;
    else k = 1;
    *kind = k;
  }
}

__global__ __launch_bounds__(256) void build_mask_kernel(
    const void* __restrict__ mraw, const int* __restrict__ roles,
    const int* __restrict__ kind, unsigned char* __restrict__ mask8,
    float* __restrict__ monf, float* __restrict__ hubf) {
  int t = blockIdx.x * 256 + threadIdx.x;
  if (t < MTOK) {
    int k = *kind;
    int v;
    if (k == 1)      v = (((const unsigned char*)mraw)[t] != 0);
    else if (k == 0) v = (((const int*)mraw)[t] != 0);
    else             v = (((const float*)mraw)[t] != 0.0f);
    mask8[t] = (unsigned char)v;
  }
  if (t < NN) {
    int mon = 0, hub = 0;
#pragma unroll
    for (int b = 0; b < BB; ++b) {
      int r = roles[b * NN + t];
      mon |= (r == 2) ? 1 : 0;
      hub |= (r == 1) ? 1 : 0;
    }
    monf[t] = (float)mon;
    hubf[t] = (float)hub;
  }
}

// ---------------- layernorm + role bias -> bf16 x, normed, h ----------------
__global__ __launch_bounds__(256) void prep_kernel(
    const float* __restrict__ x, const int* __restrict__ roles,
    const float* __restrict__ gamma, const float* __restrict__ beta,
    const float* __restrict__ role_emb,
    __bf16* __restrict__ X16, __bf16* __restrict__ N16, __bf16* __restrict__ H16) {
  int t = blockIdx.x * 4 + (threadIdx.x >> 6);
  int lane = threadIdx.x & 63;
  size_t off = (size_t)t * DD + lane * 4;
  float4 xv = *(const float4*)(x + off);
  float s = xv.x + xv.y + xv.z + xv.w;
  float ss = xv.x * xv.x + xv.y * xv.y + xv.z * xv.z + xv.w * xv.w;
#pragma unroll
  for (int m = 1; m < 64; m <<= 1) {
    s += __shfl_xor(s, m, 64);
    ss += __shfl_xor(ss, m, 64);
  }
  float mu = s * (1.0f / 256.0f);
  float var = ss * (1.0f / 256.0f) - mu * mu;
  float inv = rsqrtf(var + 1e-5f);
  float4 g = *(const float4*)(gamma + lane * 4);
  float4 be = *(const float4*)(beta + lane * 4);
  float nv[4];
  nv[0] = (xv.x - mu) * inv * g.x + be.x;
  nv[1] = (xv.y - mu) * inv * g.y + be.y;
  nv[2] = (xv.z - mu) * inv * g.z + be.z;
  nv[3] = (xv.w - mu) * inv * g.w + be.w;
  int role = roles[t];
  float4 rb = *(const float4*)(role_emb + (size_t)role * DD + lane * 4);
  float rbv[4] = {rb.x, rb.y, rb.z, rb.w};
  bf16x4 xo, no, ho;
  float xf[4] = {xv.x, xv.y, xv.z, xv.w};
#pragma unroll
  for (int q = 0; q < 4; ++q) {
    xo[q] = (__bf16)xf[q];
    no[q] = (__bf16)nv[q];
    ho[q] = (__bf16)(nv[q] + rbv[q]);
  }
  *(bf16x4*)&X16[off] = xo;
  *(bf16x4*)&N16[off] = no;
  *(bf16x4*)&H16[off] = ho;
}

// ---------------- weight transpose -> bf16 WT[n][k] ----------------
__global__ __launch_bounds__(256) void wt_kernel(
    const float* __restrict__ Wq, const float* __restrict__ Wk,
    const float* __restrict__ Ws, const float* __restrict__ Wp,
    const float* __restrict__ Wg, const float* __restrict__ Wo,
    __bf16* __restrict__ WT) {
  int z = blockIdx.z;
  const float* src;
  int K;
  size_t doff;
  switch (z) {
    case 0: src = Wq; K = 256; doff = 0; break;
    case 1: src = Wk; K = 256; doff = 65536; break;
    case 2: src = Ws; K = 256; doff = 131072; break;
    case 3: src = Wp; K = 256; doff = 196608; break;
    case 4: src = Wg; K = 512; doff = 262144; break;
    default: src = Wo; K = 256; doff = 393216; break;
  }
  int k0 = blockIdx.y * 64;
  if (k0 >= K) return;
  int n0 = blockIdx.x * 64;
  __shared__ float T[64][65];
  int tid = threadIdx.x;
#pragma unroll
  for (int p = 0; p < 16; ++p) {
    int idx = p * 256 + tid;
    int r = idx >> 6, c = idx & 63;
    T[r][c] = src[(size_t)(k0 + r) * 256 + n0 + c];
  }
  __syncthreads();
#pragma unroll
  for (int p = 0; p < 16; ++p) {
    int idx = p * 256 + tid;
    int n = idx >> 6, k = idx & 63;
    WT[doff + (size_t)(n0 + n) * K + k0 + k] = (__bf16)T[k][n];
  }
}

// ---------------- MFMA GEMM: C[16384, 256-tile] = A[.,K] @ WT^T + epilogue ----
// Tile 128 rows x 64 cols, 4 waves (2x2), wave = 64x32. BK=64.
// MODE: 0 q(*1/16->bf16 ld512) 1 k(->bf16 ld512) 2 fs(role+sqrt.5 -> two dsts)
//       3 p(->bf16 ld256) 4 gate(sigmoid*msg->bf16 ld256) 5 out(+x -> f32)
template <int K, int MODE>
__global__ __launch_bounds__(256) void gemmb_kernel(
    const __bf16* __restrict__ A0, const __bf16* __restrict__ A1,
    const __bf16* __restrict__ WT, const float* __restrict__ bias,
    const int* __restrict__ roles, const float* __restrict__ remb,
    const float* __restrict__ xf, const __bf16* __restrict__ msg16,
    void* __restrict__ dst0, void* __restrict__ dst1) {
  __shared__ __align__(16) unsigned char As[128 * 128];  // [128 rows][64 k] bf16 swz
  __shared__ __align__(16) unsigned char Bs[64 * 128];   // [64 cols][64 k] bf16 swz
  int tid = threadIdx.x;
  int w = tid >> 6, lane = tid & 63, ln15 = lane & 15, lq = lane >> 4;
  int wr = w >> 1, wc = w & 1;
  int row0 = blockIdx.y * 128, col0 = blockIdx.x * 64;
  f32x4 acc[4][2];
#pragma unroll
  for (int i = 0; i < 4; ++i)
#pragma unroll
    for (int j = 0; j < 2; ++j) acc[i][j] = (f32x4){0.f, 0.f, 0.f, 0.f};

  int lr = lane >> 3;            // 0..7 staging row within instr
  int lb = (lane & 7) * 16;      // byte within 128B row
  int sb = lb ^ ((lr & 7) << 4); // pre-swizzled source byte

  for (int kt = 0; kt < K / 64; ++kt) {
    const __bf16* Ab = A0;
    int ktl = kt;
    if (K == 512 && kt >= 4) { Ab = A1; ktl = kt - 4; }
    __syncthreads();
#pragma unroll
    for (int i2 = 0; i2 < 4; ++i2) {
      int idx = w * 4 + i2;
      int grow = row0 + idx * 8 + lr;
      gl_lds16((const unsigned char*)Ab + (size_t)grow * 512 + ktl * 128 + sb,
               As + idx * 1024);
    }
#pragma unroll
    for (int i2 = 0; i2 < 2; ++i2) {
      int idx = w * 2 + i2;
      int gcol = col0 + idx * 8 + lr;
      gl_lds16((const unsigned char*)WT + (size_t)gcol * (K * 2) + kt * 128 + sb,
               Bs + idx * 1024);
    }
    __syncthreads();
#pragma unroll
    for (int ks = 0; ks < 2; ++ks) {
      bf16x8 af[4], bfr[2];
#pragma unroll
      for (int i = 0; i < 4; ++i) {
        int rl = wr * 64 + i * 16 + ln15;
        int byteoff = (lq * 16 + ks * 64) ^ ((rl & 7) << 4);
        af[i] = *(const bf16x8*)(As + rl * 128 + byteoff);
      }
#pragma unroll
      for (int j = 0; j < 2; ++j) {
        int cl = wc * 32 + j * 16 + ln15;
        int byteoff = (lq * 16 + ks * 64) ^ ((cl & 7) << 4);
        bfr[j] = *(const bf16x8*)(Bs + cl * 128 + byteoff);
      }
#pragma unroll
      for (int i = 0; i < 4; ++i)
#pragma unroll
        for (int j = 0; j < 2; ++j) acc[i][j] = MFMA16(af[i], bfr[j], acc[i][j]);
    }
  }
  // epilogue
  float bj[2];
#pragma unroll
  for (int j = 0; j < 2; ++j) bj[j] = bias[col0 + wc * 32 + j * 16 + ln15];
#pragma unroll
  for (int i = 0; i < 4; ++i) {
#pragma unroll
    for (int ri = 0; ri < 4; ++ri) {
      int grow = row0 + wr * 64 + i * 16 + lq * 4 + ri;
#pragma unroll
      for (int j = 0; j < 2; ++j) {
        int gcol = col0 + wc * 32 + j * 16 + ln15;
        float o = acc[i][j][ri] + bj[j];
        if (MODE == 0) {
          ((__bf16*)dst0)[(size_t)grow * 512 + gcol] = (__bf16)(o * 0.0625f);
        } else if (MODE == 1) {
          ((__bf16*)dst0)[(size_t)grow * 512 + gcol] = (__bf16)o;
        } else if (MODE == 2) {
          o += remb[(size_t)roles[grow] * 256 + gcol];
          __bf16 v = (__bf16)(o * 0.70710678118f);
          ((__bf16*)dst0)[(size_t)grow * 512 + gcol] = v;
          ((__bf16*)dst1)[(size_t)grow * 512 + gcol] = v;
        } else if (MODE == 3) {
          ((__bf16*)dst0)[(size_t)grow * 256 + gcol] = (__bf16)o;
        } else if (MODE == 4) {
          float sg = 1.0f / (1.0f + __expf(-o));
          float mv = (float)msg16[(size_t)grow * 256 + gcol];
          ((__bf16*)dst0)[(size_t)grow * 256 + gcol] = (__bf16)(sg * mv);
        } else {
          ((float*)dst0)[(size_t)grow * 256 + gcol] =
              o + xf[(size_t)grow * 256 + gcol];
        }
      }
    }
  }
}

// -------- transpose Pb16 [b][token][256] -> PTE [b][272][2048] rows 0..255 ----
__global__ __launch_bounds__(256) void transpose_p_kernel(
    const __bf16* __restrict__ Pb, __bf16* __restrict__ PTE) {
  __shared__ __bf16 T[64][72];
  int bx = blockIdx.x, dt = blockIdx.y, b = blockIdx.z;
  int t = threadIdx.x;
  int tr = t >> 3, tc = (t & 7) * 8;
#pragma unroll
  for (int p = 0; p < 2; ++p) {
    int tok = p * 32 + tr;
    bf16x8 v = *(const bf16x8*)&Pb[((size_t)(b * NN + bx * 64 + tok)) * DD + dt * 64 + tc];
    *(bf16x8*)&T[tok][tc] = v;
  }
  __syncthreads();
#pragma unroll
  for (int p = 0; p < 2; ++p) {
    int dr = p * 32 + tr;
    bf16x8 v;
#pragma unroll
    for (int q = 0; q < 8; ++q) v[q] = T[tc + q][dr];
    *(bf16x8*)&PTE[((size_t)(b * 272 + dt * 64 + dr)) * NN + bx * 64 + tc] = v;
  }
}

// -------- PTE extra rows 256..271: mon, hub, ones, zeros --------
__global__ __launch_bounds__(256) void fill_pte_kernel(
    const float* __restrict__ monf, const float* __restrict__ hubf,
    __bf16* __restrict__ PTE) {
  int idx = blockIdx.x * 256 + threadIdx.x;   // [8][16][2048]
  int b = idx >> 15, r = (idx >> 11) & 15, col = idx & 2047;
  float v = (r == 0) ? monf[col] : (r == 1) ? hubf[col] : (r == 2) ? 1.0f : 0.0f;
  PTE[((size_t)(b * 272 + 256 + r)) * NN + col] = (__bf16)v;
}

// ---------------- MFMA flash attention, split-KV ----------------
// grid 512: id = rowblock*16 + half*8 + batch (XCD == batch). 4 waves x 16 rows.
// BC=32. Stats (Tm,Th,Z) ride PV as payload rows 256..258.
__global__ __launch_bounds__(256, 2) void attn_kernel(
    const __bf16* __restrict__ Grow, const __bf16* __restrict__ Gcol,
    const __bf16* __restrict__ PTE, const unsigned char* __restrict__ mask8,
    float* __restrict__ msgP0, float* __restrict__ msgP1,
    float* __restrict__ statP) {
  __shared__ __align__(16) unsigned char GcS[32 * 1024];  // [32 tok][1024B] swz
  __shared__ __align__(16) unsigned char PtS[17 * 1024];  // [272 d][64B]
  __shared__ float Elds[4 * 16 * 36];

  int tid = threadIdx.x;
  int w = tid >> 6, lane = tid & 63, ln15 = lane & 15, lq = lane >> 4;
  int id = blockIdx.x;
  int b = id & 7;
  int half = (id >> 3) & 1;
  int r0 = (id >> 4) * 64;
  size_t base = (size_t)b * NN;
  float* msgP = half ? msgP1 : msgP0;
  float* statB = statP + (size_t)half * MTOK * 6;

  bf16x8 Af[16];
  {
    const __bf16* gr = Grow + (base + r0 + w * 16 + ln15) * 512 + lq * 8;
#pragma unroll
    for (int kk = 0; kk < 16; ++kk) Af[kk] = *(const bf16x8*)(gr + kk * 32);
  }

  float m[4], T[4];
  f32x4 macc[17];
#pragma unroll
  for (int r = 0; r < 4; ++r) { m[r] = -1e30f; T[r] = 0.f; }
#pragma unroll
  for (int nt = 0; nt < 17; ++nt) macc[nt] = (f32x4){0.f, 0.f, 0.f, 0.f};

  const unsigned char* gbase =
      (const unsigned char*)Gcol + (base + half * 1024) * 1024;
  const unsigned char* pbase =
      (const unsigned char*)PTE + (size_t)b * 272 * 4096 + half * 2048;
  float* Ew = Elds + w * (16 * 36);

  for (int ch = 0; ch < 32; ++ch) {
    int c0 = half * 1024 + ch * 32;
    __syncthreads();
#pragma unroll
    for (int i = 0; i < 8; ++i) {
      int r = w * 8 + i;
      int srcb = (lane * 16) ^ ((r & 7) << 4);
      gl_lds16(gbase + (size_t)(ch * 32 + r) * 1024 + srcb, GcS + r * 1024);
    }
#pragma unroll
    for (int i = 0; i < 4; ++i) {
      int idx = w * 4 + i;
      int drow = idx * 16 + (lane >> 2);
      gl_lds16(pbase + (size_t)drow * 4096 + ch * 64 + (lane & 3) * 16,
               PtS + idx * 1024);
    }
    if (w == 0) {
      int drow = 256 + (lane >> 2);
      gl_lds16(pbase + (size_t)drow * 4096 + ch * 64 + (lane & 3) * 16,
               PtS + 16 * 1024);
    }
    __syncthreads();

    // ---- S phase ----
    f32x4 sa[2];
    sa[0] = (f32x4){0.f, 0.f, 0.f, 0.f};
    sa[1] = (f32x4){0.f, 0.f, 0.f, 0.f};
#pragma unroll
    for (int kk = 0; kk < 16; ++kk) {
#pragma unroll
      for (int jt = 0; jt < 2; ++jt) {
        int n = jt * 16 + ln15;
        int byteoff = ((lq * 16) + kk * 64) ^ ((n & 7) << 4);
        bf16x8 bv = *(const bf16x8*)(GcS + n * 1024 + byteoff);
        sa[jt] = MFMA16(Af[kk], bv, sa[jt]);
      }
    }

    // ---- masked online softmax (Z/Tm/Th via payload rows) ----
    int cm0 = mask8[base + c0 + ln15];
    int cm1 = mask8[base + c0 + 16 + ln15];
#pragma unroll
    for (int r = 0; r < 4; ++r) {
      float l0 = cm0 ? sa[0][r] : -1e30f;
      float l1 = cm1 ? sa[1][r] : -1e30f;
      float mt = fmaxf(l0, l1);
#pragma unroll
      for (int mk = 1; mk < 16; mk <<= 1) mt = fmaxf(mt, __shfl_xor(mt, mk, 16));
      float mnew = fmaxf(m[r], mt);
      if (__any(mnew > m[r])) {
        float ci = __expf(m[r] - mnew);
#pragma unroll
        for (int nt = 0; nt < 17; ++nt) macc[nt][r] *= ci;
        T[r] *= ci;
        m[r] = mnew;
      }
      float e0 = cm0 ? __expf(sa[0][r] - m[r]) : 0.f;
      float e1 = cm1 ? __expf(sa[1][r] - m[r]) : 0.f;
      float tl = e0 * sa[0][r] + e1 * sa[1][r];
#pragma unroll
      for (int mk = 1; mk < 16; mk <<= 1) tl += __shfl_xor(tl, mk, 16);
      T[r] += tl;
      Ew[(lq * 4 + r) * 36 + ln15] = e0;
      Ew[(lq * 4 + r) * 36 + 16 + ln15] = e1;
    }

    // ---- PV (17 tiles: 16 payload + stats) ----
    f32x4 e0v = *(const f32x4*)(Ew + ln15 * 36 + lq * 8);
    f32x4 e1v = *(const f32x4*)(Ew + ln15 * 36 + lq * 8 + 4);
    bf16x8 ef;
#pragma unroll
    for (int q = 0; q < 4; ++q) { ef[q] = (__bf16)e0v[q]; ef[q + 4] = (__bf16)e1v[q]; }
#pragma unroll
    for (int nt = 0; nt < 17; ++nt) {
      int drow = nt * 16 + ln15;
      bf16x8 pv = *(const bf16x8*)(PtS + drow * 64 + lq * 16);
      macc[nt] = MFMA16(ef, pv, macc[nt]);
    }
  }

  // ---- finalize: raw partials ----
#pragma unroll
  for (int r = 0; r < 4; ++r) {
    int grow = r0 + w * 16 + lq * 4 + r;
    size_t row = base + grow;
#pragma unroll
    for (int nt = 0; nt < 16; ++nt)
      msgP[row * 256 + nt * 16 + ln15] = macc[nt][r];
    float* st = statB + row * 6;
    if (ln15 == 0) { st[0] = m[r]; st[1] = T[r]; st[3] = macc[16][r]; }
    else if (ln15 == 1) st[4] = macc[16][r];
    else if (ln15 == 2) st[2] = macc[16][r];
  }
}

// ---------------- merge halves ----------------
__global__ __launch_bounds__(256) void merge_kernel(
    const float* __restrict__ msgP0, const float* __restrict__ msgP1,
    const float* __restrict__ statP, const unsigned char* __restrict__ mask8,
    __bf16* __restrict__ MSG16, float* __restrict__ entr,
    float* __restrict__ monr, float* __restrict__ hubr) {
  int row = blockIdx.x * 4 + (threadIdx.x >> 6);
  int lane = threadIdx.x & 63;
  const float* s0 = statP + (size_t)row * 6;
  const float* s1 = statP + (size_t)(MTOK + row) * 6;
  float m0 = s0[0], T0 = s0[1], Z0 = s0[2], Tm0 = s0[3], Th0 = s0[4];
  float m1 = s1[0], T1 = s1[1], Z1 = s1[2], Tm1 = s1[3], Th1 = s1[4];
  int valid = mask8[row] != 0;
  float mm = fmaxf(m0, m1);
  float c0 = __expf(m0 - mm), c1 = __expf(m1 - mm);
  float Z = c0 * Z0 + c1 * Z1;
  int ok = valid && (Z > 0.f);
  float invZ = ok ? (1.0f / Z) : 0.0f;
  float4 p0 = *(const float4*)(msgP0 + (size_t)row * 256 + lane * 4);
  float4 p1 = *(const float4*)(msgP1 + (size_t)row * 256 + lane * 4);
  bf16x4 o;
  o[0] = (__bf16)((c0 * p0.x + c1 * p1.x) * invZ);
  o[1] = (__bf16)((c0 * p0.y + c1 * p1.y) * invZ);
  o[2] = (__bf16)((c0 * p0.z + c1 * p1.z) * invZ);
  o[3] = (__bf16)((c0 * p0.w + c1 * p1.w) * invZ);
  *(bf16x4*)&MSG16[(size_t)row * 256 + lane * 4] = o;
  if (lane == 0) {
    float T = c0 * T0 + c1 * T1;
    float Tm = c0 * Tm0 + c1 * Tm1;
    float Th = c0 * Th0 + c1 * Th1;
    entr[row] = ok ? (logf(Z) + mm - T / Z) : 0.0f;
    monr[row] = ok ? (Tm * invZ) : 0.0f;
    hubr[row] = ok ? (Th * invZ) : 0.0f;
  }
}

// ---------------- final scalar reduction ----------------
__device__ __forceinline__ float block_sum(float v, float* sh) {
  __syncthreads();
  sh[threadIdx.x] = v;
  __syncthreads();
  for (int s = 128; s > 0; s >>= 1) {
    if ((int)threadIdx.x < s) sh[threadIdx.x] += sh[threadIdx.x + s];
    __syncthreads();
  }
  return sh[0];
}

__global__ __launch_bounds__(256) void reduce_kernel(
    const float* __restrict__ entr, const float* __restrict__ monr,
    const float* __restrict__ hubr, const float* __restrict__ monf,
    const float* __restrict__ hubf, float* __restrict__ out3) {
  __shared__ float sh[256];
  float es = 0.f, ms = 0.f, hs = 0.f, cmf = 0.f, chf = 0.f;
  for (int i = threadIdx.x; i < MTOK; i += 256) {
    es += entr[i]; ms += monr[i]; hs += hubr[i];
  }
  for (int j = threadIdx.x; j < NN; j += 256) { cmf += monf[j]; chf += hubf[j]; }
  float esum = block_sum(es, sh);
  float msum = block_sum(ms, sh);
  float hsum = block_sum(hs, sh);
  float cmsum = block_sum(cmf, sh);
  float chsum = block_sum(chf, sh);
  if (threadIdx.x == 0) {
    out3[0] = esum / 16384.0f;
    out3[1] = (cmsum > 0.f) ? (msum / (cmsum * 16384.0f)) : 0.0f;
    out3[2] = (chsum > 0.f) ? (hsum / (chsum * 16384.0f)) : 0.0f;
  }
}

extern "C" void kernel_launch(void* const* d_in, const int* in_sizes, int n_in,
                              void* d_out, int out_size, void* d_ws, size_t ws_size,
                              hipStream_t stream) {
  const float* x = (const float*)d_in[0];
  const int* roles = (const int*)d_in[1];
  const void* mraw = d_in[2];
  const float* gamma = (const float*)d_in[3];
  const float* beta = (const float*)d_in[4];
  const float* remb = (const float*)d_in[5];
  const float* Wq = (const float*)d_in[6];
  const float* bq = (const float*)d_in[7];
  const float* Wk = (const float*)d_in[8];
  const float* bk = (const float*)d_in[9];
  const float* Ws = (const float*)d_in[10];
  const float* bs = (const float*)d_in[11];
  const float* Wp = (const float*)d_in[12];
  const float* bp = (const float*)d_in[13];
  const float* Wo = (const float*)d_in[14];
  const float* bo = (const float*)d_in[15];
  const float* Wg = (const float*)d_in[16];
  const float* bg = (const float*)d_in[17];

  float* ws = (float*)d_ws;
  __bf16* X16 = (__bf16*)(ws + OFF_X16);
  __bf16* N16 = (__bf16*)(ws + OFF_N16);
  __bf16* H16 = (__bf16*)(ws + OFF_H16);
  __bf16* Pb16 = (__bf16*)(ws + OFF_PB);
  __bf16* Grow = (__bf16*)(ws + OFF_GROW);
  __bf16* Gcol = (__bf16*)(ws + OFF_GCOL);
  __bf16* PTE = (__bf16*)(ws + OFF_PTE);
  __bf16* WT = (__bf16*)(ws + OFF_WT);
  float* statP = ws + OFF_STAT;
  float* msgP0 = ws + OFF_MSGP0;
  float* msgP1 = ws + OFF_MSGP1;
  __bf16* MSG16 = (__bf16*)(ws + OFF_MSG16);
  __bf16* GM16 = (__bf16*)(ws + OFF_GM16);
  float* entr = ws + OFF_ENT;
  float* monr = ws + OFF_MONR;
  float* hubr = ws + OFF_HUBR;
  float* monfp = ws + OFF_MONF;
  float* hubfp = ws + OFF_HUBF;
  unsigned char* mask8 = (unsigned char*)(ws + OFF_MASK);
  int* kind = (int*)(ws + OFF_KIND);
  float* out = (float*)d_out;

  __bf16* WTq = WT;
  __bf16* WTk = WT + 65536;
  __bf16* WTs = WT + 131072;
  __bf16* WTp = WT + 196608;
  __bf16* WTg = WT + 262144;
  __bf16* WTo = WT + 393216;

  detect_mask_kernel<<<1, 256, 0, stream>>>((const unsigned char*)mraw, kind);
  build_mask_kernel<<<64, 256, 0, stream>>>(mraw, roles, kind, mask8, monfp, hubfp);
  prep_kernel<<<4096, 256, 0, stream>>>(x, roles, gamma, beta, remb, X16, N16, H16);
  wt_kernel<<<dim3(4, 8, 6), 256, 0, stream>>>(Wq, Wk, Ws, Wp, Wg, Wo, WT);
  dim3 gg(4, 128);
  gemmb_kernel<256, 0><<<gg, 256, 0, stream>>>(H16, nullptr, WTq, bq, nullptr,
                                               nullptr, nullptr, nullptr, Grow, nullptr);
  gemmb_kernel<256, 1><<<gg, 256, 0, stream>>>(H16, nullptr, WTk, bk, nullptr,
                                               nullptr, nullptr, nullptr, Gcol, nullptr);
  gemmb_kernel<256, 2><<<gg, 256, 0, stream>>>(H16, nullptr, WTs, bs, roles,
                                               remb, nullptr, nullptr, Grow + 256, Gcol + 256);
  gemmb_kernel<256, 3><<<gg, 256, 0, stream>>>(N16, nullptr, WTp, bp, nullptr,
                                               nullptr, nullptr, nullptr, Pb16, nullptr);
  transpose_p_kernel<<<dim3(32, 4, 8), 256, 0, stream>>>(Pb16, PTE);
  fill_pte_kernel<<<1024, 256, 0, stream>>>(monfp, hubfp, PTE);
  attn_kernel<<<512, 256, 0, stream>>>(Grow, Gcol, PTE, mask8, msgP0, msgP1, statP);
  merge_kernel<<<4096, 256, 0, stream>>>(msgP0, msgP1, statP, mask8, MSG16,
                                         entr, monr, hubr);
  gemmb_kernel<512, 4><<<gg, 256, 0, stream>>>(X16, MSG16, WTg, bg, nullptr,
                                               nullptr, nullptr, MSG16, GM16, nullptr);
  gemmb_kernel<256, 5><<<gg, 256, 0, stream>>>(GM16, nullptr, WTo, bo, nullptr,
                                               nullptr, x, nullptr, out, nullptr);
  reduce_kernel<<<1, 256, 0, stream>>>(entr, monr, hubr, monfp, hubfp,
                                       out + 4194304);
}

// Round 4
// 231.358 us; speedup vs baseline: 7.0718x; 1.0004x over previous
//
#include <hip/hip_runtime.h>
#include <math.h>

#define BB 8
#define NN 2048
#define DD 256
#define MTOK 16384

typedef __bf16 bf16x8 __attribute__((ext_vector_type(8)));
typedef __bf16 bf16x4 __attribute__((ext_vector_type(4)));
typedef float f32x4 __attribute__((ext_vector_type(4)));

#define MFMA16(a, b, c) __builtin_amdgcn_mfma_f32_16x16x32_bf16(a, b, c, 0, 0, 0)

// ---- workspace layout (float offsets) ----
#define OFF_X16    0ull          // bf16 [16384][256]
#define OFF_N16    2097152ull    // bf16 [16384][256]
#define OFF_H16    4194304ull    // bf16 [16384][256]
#define OFF_PB     6291456ull    // (free)
#define OFF_GROW   8388608ull    // bf16 [16384][512]  ([q/16 | fs*sqrt(.5)])
#define OFF_GCOL   12582912ull   // bf16 [16384][512]  ([k    | fs*sqrt(.5)])
#define OFF_PTE    16777216ull   // bf16 [8][272][2048]
#define OFF_WT     19005440ull   // bf16 weights transposed
#define OFF_STAT   19234816ull   // f32 [64][4] reduce partials
#define OFF_ENT    23625728ull
#define OFF_MONR   23642112ull
#define OFF_HUBR   23658496ull
#define OFF_MONF   23674880ull
#define OFF_HUBF   23676928ull
#define OFF_MASK   23678976ull   // 16384 bytes
#define OFF_KIND   23683072ull
// aliases (dead-region reuse):
#define OFF_MSG16  OFF_N16       // bf16 [16384][256]; N16 dead after proj z=3
#define OFF_GM16   OFF_H16       // bf16 [16384][256]; H16 dead after proj z=2

__device__ __forceinline__ void gl_lds16(const void* g, void* l) {
  __builtin_amdgcn_global_load_lds(
      (const __attribute__((address_space(1))) unsigned int*)g,
      (__attribute__((address_space(3))) unsigned int*)l, 16, 0, 0);
}

// ---------------- mask dtype detection ----------------
__global__ __launch_bounds__(256) void detect_mask_kernel(
    const unsigned char* __restrict__ mraw, int* __restrict__ kind) {
  __shared__ int c0s, c1s;
  if (threadIdx.x == 0) { c0s = 0; c1s = 0; }
  __syncthreads();
  int c0 = 0, c1 = 0;
  for (int i = threadIdx.x; i < MTOK; i += 256) {
    int nz = (mraw[i] != 0) ? 1 : 0;
    if ((i & 3) == 0) c0 += nz; else c1 += nz;
  }
  atomicAdd(&c0s, c0);
  atomicAdd(&c1s, c1);
  __syncthreads();
  if (threadIdx.x == 0) {
    int k;
    if (c0s == 0) k = 2;
    else if (c1s == 0) k = 0;
    else k = 1;
    *kind = k;
  }
}

__global__ __launch_bounds__(256) void build_mask_kernel(
    const void* __restrict__ mraw, const int* __restrict__ roles,
    const int* __restrict__ kind, unsigned char* __restrict__ mask8,
    float* __restrict__ monf, float* __restrict__ hubf) {
  int t = blockIdx.x * 256 + threadIdx.x;
  if (t < MTOK) {
    int k = *kind;
    int v;
    if (k == 1)      v = (((const unsigned char*)mraw)[t] != 0);
    else if (k == 0) v = (((const int*)mraw)[t] != 0);
    else             v = (((const float*)mraw)[t] != 0.0f);
    mask8[t] = (unsigned char)v;
  }
  if (t < NN) {
    int mon = 0, hub = 0;
#pragma unroll
    for (int b = 0; b < BB; ++b) {
      int r = roles[b * NN + t];
      mon |= (r == 2) ? 1 : 0;
      hub |= (r == 1) ? 1 : 0;
    }
    monf[t] = (float)mon;
    hubf[t] = (float)hub;
  }
}

// ---------------- layernorm + role bias -> bf16 x, normed, h ----------------
__global__ __launch_bounds__(256) void prep_kernel(
    const float* __restrict__ x, const int* __restrict__ roles,
    const float* __restrict__ gamma, const float* __restrict__ beta,
    const float* __restrict__ role_emb,
    __bf16* __restrict__ X16, __bf16* __restrict__ N16, __bf16* __restrict__ H16) {
  int t = blockIdx.x * 4 + (threadIdx.x >> 6);
  int lane = threadIdx.x & 63;
  size_t off = (size_t)t * DD + lane * 4;
  float4 xv = *(const float4*)(x + off);
  float s = xv.x + xv.y + xv.z + xv.w;
  float ss = xv.x * xv.x + xv.y * xv.y + xv.z * xv.z + xv.w * xv.w;
#pragma unroll
  for (int m = 1; m < 64; m <<= 1) {
    s += __shfl_xor(s, m, 64);
    ss += __shfl_xor(ss, m, 64);
  }
  float mu = s * (1.0f / 256.0f);
  float var = ss * (1.0f / 256.0f) - mu * mu;
  float inv = rsqrtf(var + 1e-5f);
  float4 g = *(const float4*)(gamma + lane * 4);
  float4 be = *(const float4*)(beta + lane * 4);
  float nv[4];
  nv[0] = (xv.x - mu) * inv * g.x + be.x;
  nv[1] = (xv.y - mu) * inv * g.y + be.y;
  nv[2] = (xv.z - mu) * inv * g.z + be.z;
  nv[3] = (xv.w - mu) * inv * g.w + be.w;
  int role = roles[t];
  float4 rb = *(const float4*)(role_emb + (size_t)role * DD + lane * 4);
  float rbv[4] = {rb.x, rb.y, rb.z, rb.w};
  bf16x4 xo, no, ho;
  float xf[4] = {xv.x, xv.y, xv.z, xv.w};
#pragma unroll
  for (int q = 0; q < 4; ++q) {
    xo[q] = (__bf16)xf[q];
    no[q] = (__bf16)nv[q];
    ho[q] = (__bf16)(nv[q] + rbv[q]);
  }
  *(bf16x4*)&X16[off] = xo;
  *(bf16x4*)&N16[off] = no;
  *(bf16x4*)&H16[off] = ho;
}

// ---------------- weight transpose -> bf16 WT[n][k] ----------------
__global__ __launch_bounds__(256) void wt_kernel(
    const float* __restrict__ Wq, const float* __restrict__ Wk,
    const float* __restrict__ Ws, const float* __restrict__ Wp,
    const float* __restrict__ Wg, const float* __restrict__ Wo,
    __bf16* __restrict__ WT) {
  int z = blockIdx.z;
  const float* src;
  int K;
  size_t doff;
  switch (z) {
    case 0: src = Wq; K = 256; doff = 0; break;
    case 1: src = Wk; K = 256; doff = 65536; break;
    case 2: src = Ws; K = 256; doff = 131072; break;
    case 3: src = Wp; K = 256; doff = 196608; break;
    case 4: src = Wg; K = 512; doff = 262144; break;
    default: src = Wo; K = 256; doff = 393216; break;
  }
  int k0 = blockIdx.y * 64;
  if (k0 >= K) return;
  int n0 = blockIdx.x * 64;
  __shared__ float T[64][65];
  int tid = threadIdx.x;
#pragma unroll
  for (int p = 0; p < 16; ++p) {
    int idx = p * 256 + tid;
    int r = idx >> 6, c = idx & 63;
    T[r][c] = src[(size_t)(k0 + r) * 256 + n0 + c];
  }
  __syncthreads();
#pragma unroll
  for (int p = 0; p < 16; ++p) {
    int idx = p * 256 + tid;
    int n = idx >> 6, k = idx & 63;
    WT[doff + (size_t)(n0 + n) * K + k0 + k] = (__bf16)T[k][n];
  }
}

// -------- fused q/k/fs/p projections (z = 0..3), K=256, tile 128x64 --------
__global__ __launch_bounds__(256) void proj4_kernel(
    const __bf16* __restrict__ H16, const __bf16* __restrict__ N16,
    const __bf16* __restrict__ WT,
    const float* __restrict__ bq, const float* __restrict__ bk,
    const float* __restrict__ bs, const float* __restrict__ bp,
    const int* __restrict__ roles, const float* __restrict__ remb,
    __bf16* __restrict__ Grow, __bf16* __restrict__ Gcol,
    __bf16* __restrict__ PTE) {
  __shared__ __align__(16) unsigned char As[128 * 128];
  __shared__ __align__(16) unsigned char Bs[64 * 128];
  int z = blockIdx.z;
  const __bf16* A = (z == 3) ? N16 : H16;
  const __bf16* W = WT + (size_t)z * 65536;
  const float* bias = (z == 0) ? bq : (z == 1) ? bk : (z == 2) ? bs : bp;

  int tid = threadIdx.x;
  int w = tid >> 6, lane = tid & 63, ln15 = lane & 15, lq = lane >> 4;
  int wr = w >> 1, wc = w & 1;
  int row0 = blockIdx.y * 128, col0 = blockIdx.x * 64;
  f32x4 acc[4][2];
#pragma unroll
  for (int i = 0; i < 4; ++i)
#pragma unroll
    for (int j = 0; j < 2; ++j) acc[i][j] = (f32x4){0.f, 0.f, 0.f, 0.f};

  int lr = lane >> 3;
  int sb = ((lane & 7) * 16) ^ ((lr & 7) << 4);

  for (int kt = 0; kt < 4; ++kt) {
    __syncthreads();
#pragma unroll
    for (int i2 = 0; i2 < 4; ++i2) {
      int idx = w * 4 + i2;
      int grow = row0 + idx * 8 + lr;
      gl_lds16((const unsigned char*)A + (size_t)grow * 512 + kt * 128 + sb,
               As + idx * 1024);
    }
#pragma unroll
    for (int i2 = 0; i2 < 2; ++i2) {
      int idx = w * 2 + i2;
      int gcol = col0 + idx * 8 + lr;
      gl_lds16((const unsigned char*)W + (size_t)gcol * 512 + kt * 128 + sb,
               Bs + idx * 1024);
    }
    __syncthreads();
#pragma unroll
    for (int ks = 0; ks < 2; ++ks) {
      bf16x8 af[4], bfr[2];
#pragma unroll
      for (int i = 0; i < 4; ++i) {
        int rl = wr * 64 + i * 16 + ln15;
        int byteoff = (lq * 16 + ks * 64) ^ ((rl & 7) << 4);
        af[i] = *(const bf16x8*)(As + rl * 128 + byteoff);
      }
#pragma unroll
      for (int j = 0; j < 2; ++j) {
        int cl = wc * 32 + j * 16 + ln15;
        int byteoff = (lq * 16 + ks * 64) ^ ((cl & 7) << 4);
        bfr[j] = *(const bf16x8*)(Bs + cl * 128 + byteoff);
      }
#pragma unroll
      for (int i = 0; i < 4; ++i)
#pragma unroll
        for (int j = 0; j < 2; ++j) acc[i][j] = MFMA16(af[i], bfr[j], acc[i][j]);
    }
  }
  float bj[2];
#pragma unroll
  for (int j = 0; j < 2; ++j) bj[j] = bias[col0 + wc * 32 + j * 16 + ln15];
#pragma unroll
  for (int i = 0; i < 4; ++i) {
#pragma unroll
    for (int j = 0; j < 2; ++j) {
      int gcol = col0 + wc * 32 + j * 16 + ln15;
      int growb = row0 + wr * 64 + i * 16 + lq * 4;
      float o[4];
#pragma unroll
      for (int ri = 0; ri < 4; ++ri) o[ri] = acc[i][j][ri] + bj[j];
      if (z == 0) {
#pragma unroll
        for (int ri = 0; ri < 4; ++ri)
          Grow[(size_t)(growb + ri) * 512 + gcol] = (__bf16)(o[ri] * 0.0625f);
      } else if (z == 1) {
#pragma unroll
        for (int ri = 0; ri < 4; ++ri)
          Gcol[(size_t)(growb + ri) * 512 + gcol] = (__bf16)o[ri];
      } else if (z == 2) {
#pragma unroll
        for (int ri = 0; ri < 4; ++ri) {
          float oo = o[ri] + remb[(size_t)roles[growb + ri] * 256 + gcol];
          __bf16 v = (__bf16)(oo * 0.70710678118f);
          Grow[(size_t)(growb + ri) * 512 + 256 + gcol] = v;
          Gcol[(size_t)(growb + ri) * 512 + 256 + gcol] = v;
        }
      } else {
        bf16x4 v;
#pragma unroll
        for (int ri = 0; ri < 4; ++ri) v[ri] = (__bf16)o[ri];
        int b = growb >> 11, tok = growb & 2047;
        *(bf16x4*)&PTE[((size_t)(b * 272 + gcol)) * 2048 + tok] = v;
      }
    }
  }
}

// -------- PTE extra rows 256..271: mon, hub, ones, zeros --------
__global__ __launch_bounds__(256) void fill_pte_kernel(
    const float* __restrict__ monf, const float* __restrict__ hubf,
    __bf16* __restrict__ PTE) {
  int idx = blockIdx.x * 256 + threadIdx.x;   // [8][16][2048]
  int b = idx >> 15, r = (idx >> 11) & 15, col = idx & 2047;
  float v = (r == 0) ? monf[col] : (r == 1) ? hubf[col] : (r == 2) ? 1.0f : 0.0f;
  PTE[((size_t)(b * 272 + 256 + r)) * NN + col] = (__bf16)v;
}

// ---------------- MFMA flash attention v3 ----------------
// grid 256 (id = rowblock*8 + batch, so XCD == batch), 4 waves x 16 q-rows.
// BC=32, full KV per block (64 chunks). Swapped QK^T: S = mfma(Gc, Grow) with
// column-permuted kv tiles so each lane holds e for kv-cols lq*8..+8 of its
// q-row (ln15) -> PV A-fragment is lane-local, no LDS E round-trip.
// Pipelined double-buffer staging: one __syncthreads per chunk (implicit
// vmcnt(0) drains the stage issued at the top of the iteration).
__global__ __launch_bounds__(256) void attn_kernel(
    const __bf16* __restrict__ Grow, const __bf16* __restrict__ Gcol,
    const __bf16* __restrict__ PTE, const unsigned char* __restrict__ mask8,
    __bf16* __restrict__ MSG16, float* __restrict__ entr,
    float* __restrict__ monr, float* __restrict__ hubr) {
  __shared__ __align__(16) unsigned char GcS[2][32768];  // [32 kv][1024B] swz
  __shared__ __align__(16) unsigned char PtS[2][17408];  // [272 d][64B]

  int tid = threadIdx.x;
  int w = tid >> 6, lane = tid & 63, ln15 = lane & 15, lq = lane >> 4;
  int id = blockIdx.x;
  int b = id & 7;
  int r0 = (id >> 3) * 64;
  size_t base = (size_t)b * NN;

  const unsigned char* gbase = (const unsigned char*)Gcol + base * 1024;
  const unsigned char* pbase = (const unsigned char*)PTE + (size_t)b * 272 * 4096;

  // A fragments (q rows), resident all kernel
  bf16x8 Af[16];
  {
    const __bf16* gr = Grow + (base + r0 + w * 16 + ln15) * 512 + lq * 8;
#pragma unroll
    for (int kk = 0; kk < 16; ++kk) Af[kk] = *(const bf16x8*)(gr + kk * 32);
  }

  float m = -1e30f, T = 0.f;   // per-lane state for q-row (w*16 + ln15)
  f32x4 macc[17];
#pragma unroll
  for (int nt = 0; nt < 17; ++nt) macc[nt] = (f32x4){0.f, 0.f, 0.f, 0.f};

  auto STAGE = [&](int ch, int buf) {
#pragma unroll
    for (int i = 0; i < 8; ++i) {
      int r = w * 8 + i;
      int s = (((r & 3) | (((r >> 3) & 1) << 2))) << 4;
      gl_lds16(gbase + (size_t)(ch * 32 + r) * 1024 + ((lane * 16) ^ s),
               &GcS[buf][r * 1024]);
    }
#pragma unroll
    for (int i = 0; i < 4; ++i) {
      int idx = w * 4 + i;
      int drow = idx * 16 + (lane >> 2);
      gl_lds16(pbase + (size_t)drow * 4096 + ch * 64 + (lane & 3) * 16,
               &PtS[buf][idx * 1024]);
    }
    if (w == 0) {
      int drow = 256 + (lane >> 2);
      gl_lds16(pbase + (size_t)drow * 4096 + ch * 64 + (lane & 3) * 16,
               &PtS[buf][16 * 1024]);
    }
  };

  STAGE(0, 0);
  __syncthreads();

  for (int ch = 0; ch < 64; ++ch) {
    int cur = ch & 1;
    if (ch < 63) STAGE(ch + 1, cur ^ 1);

    // ---- S phase (swapped, col-permuted) ----
    f32x4 sa0 = (f32x4){0.f, 0.f, 0.f, 0.f};
    f32x4 sa1 = (f32x4){0.f, 0.f, 0.f, 0.f};
    int n0 = ((ln15 >> 2) * 8) + (ln15 & 3);
    int n1 = n0 + 4;
    int s0 = (((n0 & 3) | (((n0 >> 3) & 1) << 2))) << 4;
    int s1 = (((n1 & 3) | (((n1 >> 3) & 1) << 2))) << 4;
#pragma unroll
    for (int kk = 0; kk < 16; ++kk) {
      bf16x8 bv0 = *(const bf16x8*)&GcS[cur][n0 * 1024 + ((lq * 16 + kk * 64) ^ s0)];
      sa0 = MFMA16(bv0, Af[kk], sa0);
      bf16x8 bv1 = *(const bf16x8*)&GcS[cur][n1 * 1024 + ((lq * 16 + kk * 64) ^ s1)];
      sa1 = MFMA16(bv1, Af[kk], sa1);
    }
    // lane holds S[q-row = w*16+ln15][kv = ch*32 + lq*8 + i], i=0..7
    float sv[8] = {sa0[0], sa0[1], sa0[2], sa0[3], sa1[0], sa1[1], sa1[2], sa1[3]};
    unsigned long long mk =
        *(const unsigned long long*)(mask8 + base + (size_t)ch * 32 + lq * 8);

    // ---- lane-local masked online softmax ----
    float mt = -1e30f;
#pragma unroll
    for (int i = 0; i < 8; ++i) {
      float li = ((mk >> (8 * i)) & 0xffull) ? sv[i] : -1e30f;
      mt = fmaxf(mt, li);
    }
    mt = fmaxf(mt, __shfl_xor(mt, 16));
    mt = fmaxf(mt, __shfl_xor(mt, 32));
    float mnew = fmaxf(m, mt);
    if (__any(mnew > m + 8.0f)) {      // defer-max threshold (T13)
      float ci = __expf(m - mnew);
      float cir[4];
#pragma unroll
      for (int r = 0; r < 4; ++r)
        cir[r] = __shfl(ci, (lane & 48) + ((lane >> 2) & 12) + r);
#pragma unroll
      for (int nt = 0; nt < 17; ++nt) {
        macc[nt][0] *= cir[0]; macc[nt][1] *= cir[1];
        macc[nt][2] *= cir[2]; macc[nt][3] *= cir[3];
      }
      T *= ci;
      m = mnew;
    }
    float e[8], tl = 0.f;
#pragma unroll
    for (int i = 0; i < 8; ++i) {
      float ei = ((mk >> (8 * i)) & 0xffull) ? __expf(sv[i] - m) : 0.f;
      e[i] = ei;
      tl += ei * sv[i];
    }
    tl += __shfl_xor(tl, 16);
    tl += __shfl_xor(tl, 32);
    T += tl;
    bf16x8 ef;
#pragma unroll
    for (int i = 0; i < 8; ++i) ef[i] = (__bf16)e[i];

    // ---- PV (17 tiles: 16 payload + stats[mon,hub,ones]) ----
#pragma unroll
    for (int nt = 0; nt < 17; ++nt) {
      int drow = nt * 16 + ln15;
      bf16x8 pv = *(const bf16x8*)&PtS[cur][drow * 64 + lq * 16];
      macc[nt] = MFMA16(ef, pv, macc[nt]);
    }
    __syncthreads();   // drains this iter's stage (vmcnt 0) + read fence
  }

  // ---- finalize (macc rows = q-rows r0 + w*16 + lq*4 + r) ----
#pragma unroll
  for (int r = 0; r < 4; ++r) {
    int grow = r0 + w * 16 + lq * 4 + r;
    int valid = mask8[base + grow] != 0;
    float Z  = __shfl(macc[16][r], (lane & 48) + 2);
    float Tm = __shfl(macc[16][r], (lane & 48) + 0);
    float Th = __shfl(macc[16][r], (lane & 48) + 1);
    int ok = valid && (Z > 0.f);
    float invZ = ok ? (1.0f / Z) : 0.f;
#pragma unroll
    for (int nt = 0; nt < 16; ++nt)
      MSG16[(base + grow) * 256 + nt * 16 + ln15] = (__bf16)(macc[nt][r] * invZ);
    float Tr = __shfl(T, (lane & 48) + ((lane >> 2) & 12) + r);
    float mr = __shfl(m, (lane & 48) + ((lane >> 2) & 12) + r);
    if (ln15 == 0) {
      entr[base + grow] = ok ? (__logf(Z) + mr - Tr / Z) : 0.f;
      monr[base + grow] = ok ? (Tm * invZ) : 0.f;
      hubr[base + grow] = ok ? (Th * invZ) : 0.f;
    }
  }
}

// ---------------- MFMA GEMM (gate / out) ----------------
// MODE 4: gm = bf16(sigmoid([x|msg]@Wg+bg) * msg); MODE 5: out = x + gm@Wo + bo
template <int K, int MODE>
__global__ __launch_bounds__(256) void gemmb_kernel(
    const __bf16* __restrict__ A0, const __bf16* __restrict__ A1,
    const __bf16* __restrict__ WT, const float* __restrict__ bias,
    const float* __restrict__ xf, const __bf16* __restrict__ msg16,
    void* __restrict__ dst0) {
  __shared__ __align__(16) unsigned char As[128 * 128];
  __shared__ __align__(16) unsigned char Bs[64 * 128];
  int tid = threadIdx.x;
  int w = tid >> 6, lane = tid & 63, ln15 = lane & 15, lq = lane >> 4;
  int wr = w >> 1, wc = w & 1;
  int row0 = blockIdx.y * 128, col0 = blockIdx.x * 64;
  f32x4 acc[4][2];
#pragma unroll
  for (int i = 0; i < 4; ++i)
#pragma unroll
    for (int j = 0; j < 2; ++j) acc[i][j] = (f32x4){0.f, 0.f, 0.f, 0.f};

  int lr = lane >> 3;
  int sb = ((lane & 7) * 16) ^ ((lr & 7) << 4);

  for (int kt = 0; kt < K / 64; ++kt) {
    const __bf16* Ab = A0;
    int ktl = kt;
    if (K == 512 && kt >= 4) { Ab = A1; ktl = kt - 4; }
    __syncthreads();
#pragma unroll
    for (int i2 = 0; i2 < 4; ++i2) {
      int idx = w * 4 + i2;
      int grow = row0 + idx * 8 + lr;
      gl_lds16((const unsigned char*)Ab + (size_t)grow * 512 + ktl * 128 + sb,
               As + idx * 1024);
    }
#pragma unroll
    for (int i2 = 0; i2 < 2; ++i2) {
      int idx = w * 2 + i2;
      int gcol = col0 + idx * 8 + lr;
      gl_lds16((const unsigned char*)WT + (size_t)gcol * (K * 2) + kt * 128 + sb,
               Bs + idx * 1024);
    }
    __syncthreads();
#pragma unroll
    for (int ks = 0; ks < 2; ++ks) {
      bf16x8 af[4], bfr[2];
#pragma unroll
      for (int i = 0; i < 4; ++i) {
        int rl = wr * 64 + i * 16 + ln15;
        int byteoff = (lq * 16 + ks * 64) ^ ((rl & 7) << 4);
        af[i] = *(const bf16x8*)(As + rl * 128 + byteoff);
      }
#pragma unroll
      for (int j = 0; j < 2; ++j) {
        int cl = wc * 32 + j * 16 + ln15;
        int byteoff = (lq * 16 + ks * 64) ^ ((cl & 7) << 4);
        bfr[j] = *(const bf16x8*)(Bs + cl * 128 + byteoff);
      }
#pragma unroll
      for (int i = 0; i < 4; ++i)
#pragma unroll
        for (int j = 0; j < 2; ++j) acc[i][j] = MFMA16(af[i], bfr[j], acc[i][j]);
    }
  }
  float bj[2];
#pragma unroll
  for (int j = 0; j < 2; ++j) bj[j] = bias[col0 + wc * 32 + j * 16 + ln15];
#pragma unroll
  for (int i = 0; i < 4; ++i) {
#pragma unroll
    for (int ri = 0; ri < 4; ++ri) {
      int grow = row0 + wr * 64 + i * 16 + lq * 4 + ri;
#pragma unroll
      for (int j = 0; j < 2; ++j) {
        int gcol = col0 + wc * 32 + j * 16 + ln15;
        float o = acc[i][j][ri] + bj[j];
        if (MODE == 4) {
          float sg = 1.0f / (1.0f + __expf(-o));
          float mv = (float)msg16[(size_t)grow * 256 + gcol];
          ((__bf16*)dst0)[(size_t)grow * 256 + gcol] = (__bf16)(sg * mv);
        } else {
          ((float*)dst0)[(size_t)grow * 256 + gcol] =
              o + xf[(size_t)grow * 256 + gcol];
        }
      }
    }
  }
}

// ---------------- two-stage scalar reduction ----------------
__device__ __forceinline__ float block_sum(float v, float* sh) {
  __syncthreads();
  sh[threadIdx.x] = v;
  __syncthreads();
  for (int s = 128; s > 0; s >>= 1) {
    if ((int)threadIdx.x < s) sh[threadIdx.x] += sh[threadIdx.x + s];
    __syncthreads();
  }
  return sh[0];
}

__global__ __launch_bounds__(256) void reduce1_kernel(
    const float* __restrict__ entr, const float* __restrict__ monr,
    const float* __restrict__ hubr, float* __restrict__ partial) {
  __shared__ float sh[256];
  int t = blockIdx.x * 256 + threadIdx.x;
  float es = entr[t], ms = monr[t], hs = hubr[t];
  float e = block_sum(es, sh);
  float mo = block_sum(ms, sh);
  float hu = block_sum(hs, sh);
  if (threadIdx.x == 0) {
    partial[blockIdx.x * 4 + 0] = e;
    partial[blockIdx.x * 4 + 1] = mo;
    partial[blockIdx.x * 4 + 2] = hu;
  }
}

__global__ __launch_bounds__(256) void reduce2_kernel(
    const float* __restrict__ partial, const float* __restrict__ monf,
    const float* __restrict__ hubf, float* __restrict__ out3) {
  __shared__ float sh[256];
  float es = 0.f, ms = 0.f, hs = 0.f, cmf = 0.f, chf = 0.f;
  if (threadIdx.x < 64) {
    es = partial[threadIdx.x * 4 + 0];
    ms = partial[threadIdx.x * 4 + 1];
    hs = partial[threadIdx.x * 4 + 2];
  }
  for (int j = threadIdx.x; j < NN; j += 256) { cmf += monf[j]; chf += hubf[j]; }
  float esum = block_sum(es, sh);
  float msum = block_sum(ms, sh);
  float hsum = block_sum(hs, sh);
  float cmsum = block_sum(cmf, sh);
  float chsum = block_sum(chf, sh);
  if (threadIdx.x == 0) {
    out3[0] = esum / 16384.0f;
    out3[1] = (cmsum > 0.f) ? (msum / (cmsum * 16384.0f)) : 0.0f;
    out3[2] = (chsum > 0.f) ? (hsum / (chsum * 16384.0f)) : 0.0f;
  }
}

extern "C" void kernel_launch(void* const* d_in, const int* in_sizes, int n_in,
                              void* d_out, int out_size, void* d_ws, size_t ws_size,
                              hipStream_t stream) {
  const float* x = (const float*)d_in[0];
  const int* roles = (const int*)d_in[1];
  const void* mraw = d_in[2];
  const float* gamma = (const float*)d_in[3];
  const float* beta = (const float*)d_in[4];
  const float* remb = (const float*)d_in[5];
  const float* Wq = (const float*)d_in[6];
  const float* bq = (const float*)d_in[7];
  const float* Wk = (const float*)d_in[8];
  const float* bk = (const float*)d_in[9];
  const float* Ws = (const float*)d_in[10];
  const float* bs = (const float*)d_in[11];
  const float* Wp = (const float*)d_in[12];
  const float* bp = (const float*)d_in[13];
  const float* Wo = (const float*)d_in[14];
  const float* bo = (const float*)d_in[15];
  const float* Wg = (const float*)d_in[16];
  const float* bg = (const float*)d_in[17];

  float* ws = (float*)d_ws;
  __bf16* X16 = (__bf16*)(ws + OFF_X16);
  __bf16* N16 = (__bf16*)(ws + OFF_N16);
  __bf16* H16 = (__bf16*)(ws + OFF_H16);
  __bf16* Grow = (__bf16*)(ws + OFF_GROW);
  __bf16* Gcol = (__bf16*)(ws + OFF_GCOL);
  __bf16* PTE = (__bf16*)(ws + OFF_PTE);
  __bf16* WT = (__bf16*)(ws + OFF_WT);
  float* partial = ws + OFF_STAT;
  __bf16* MSG16 = (__bf16*)(ws + OFF_MSG16);
  __bf16* GM16 = (__bf16*)(ws + OFF_GM16);
  float* entr = ws + OFF_ENT;
  float* monr = ws + OFF_MONR;
  float* hubr = ws + OFF_HUBR;
  float* monfp = ws + OFF_MONF;
  float* hubfp = ws + OFF_HUBF;
  unsigned char* mask8 = (unsigned char*)(ws + OFF_MASK);
  int* kind = (int*)(ws + OFF_KIND);
  float* out = (float*)d_out;

  __bf16* WTg = WT + 262144;
  __bf16* WTo = WT + 393216;

  detect_mask_kernel<<<1, 256, 0, stream>>>((const unsigned char*)mraw, kind);
  build_mask_kernel<<<64, 256, 0, stream>>>(mraw, roles, kind, mask8, monfp, hubfp);
  prep_kernel<<<4096, 256, 0, stream>>>(x, roles, gamma, beta, remb, X16, N16, H16);
  wt_kernel<<<dim3(4, 8, 6), 256, 0, stream>>>(Wq, Wk, Ws, Wp, Wg, Wo, WT);
  proj4_kernel<<<dim3(4, 128, 4), 256, 0, stream>>>(
      H16, N16, WT, bq, bk, bs, bp, roles, remb, Grow, Gcol, PTE);
  fill_pte_kernel<<<1024, 256, 0, stream>>>(monfp, hubfp, PTE);
  attn_kernel<<<256, 256, 0, stream>>>(Grow, Gcol, PTE, mask8, MSG16,
                                       entr, monr, hubr);
  dim3 gg(4, 128);
  gemmb_kernel<512, 4><<<gg, 256, 0, stream>>>(X16, MSG16, WTg, bg, nullptr,
                                               MSG16, GM16);
  gemmb_kernel<256, 5><<<gg, 256, 0, stream>>>(GM16, nullptr, WTo, bo, x,
                                               nullptr, out);
  reduce1_kernel<<<64, 256, 0, stream>>>(entr, monr, hubr, partial);
  reduce2_kernel<<<1, 256, 0, stream>>>(partial, monfp, hubfp, out + 4194304);
}